// Round 10
// baseline (248.135 us; speedup 1.0000x reference)
//
#include <hip/hip_runtime.h>
#include <float.h>

typedef unsigned long long u64;
typedef unsigned int u32;
typedef unsigned short u16;

#define NPTS 4096
#define CDIM 64
#define BATCH 8
#define KSEL 20

// ws layout in float-slots (total 24.25 MB; r9 proved ws >= 26.6 MB):
//   [0, 1M)   xth (2M u16)         -> y1 overlays [0,2M) after k2
//   [1M, 2M)  xtl (2M u16)
//   [2M, 4M)  cand (2M u32)        (k2 writes, k2b3 reads)
//   [4M, 6M)  xtf (fp32 points)    (p1 writes, k2b3 reads)
//   [6M, +32K) sq
#define F_XTL (BATCH * NPTS * 32)               // 1M
#define F_CAND (2 * BATCH * NPTS * 32)          // 2M
#define F_XTF (4 * BATCH * NPTS * 32)           // 4M
#define F_SQ (6 * BATCH * NPTS * 32)            // 6M

typedef __attribute__((ext_vector_type(8))) short short8v;   // 8 bf16 (4 VGPR)
typedef __attribute__((ext_vector_type(16))) float float16v; // MFMA 32x32 acc

#define MFMA32(a, b, c) __builtin_amdgcn_mfma_f32_32x32x16_bf16(a, b, c, 0, 0, 0)

__device__ __forceinline__ u32 ordf(float f) {
    u32 u = __float_as_uint(f);
    return (u >> 31) ? ~u : (u | 0x80000000u);
}
__device__ __forceinline__ u32 umaxu(u32 a, u32 b) { return a > b ? a : b; }
__device__ __forceinline__ u32 uminu(u32 a, u32 b) { return a < b ? a : b; }

__device__ __forceinline__ void load_lds_16(const void* g, void* l) {
    __builtin_amdgcn_global_load_lds(
        (const __attribute__((address_space(1))) unsigned int*)g,
        (__attribute__((address_space(3))) unsigned int*)l, 16, 0, 0);
}

#define CE(i, j) { u32 a_ = c[i], b_ = c[j]; c[i] = umaxu(a_, b_); c[j] = uminu(a_, b_); }

// Batcher odd-even merge sort, 16 u32 keys, descending. 63 CEs. (validated r7-r9)
__device__ __forceinline__ void sort16_desc(u32 (&c)[16]) {
    CE(0,1) CE(2,3) CE(4,5) CE(6,7) CE(8,9) CE(10,11) CE(12,13) CE(14,15)
    CE(0,2) CE(1,3) CE(4,6) CE(5,7) CE(8,10) CE(9,11) CE(12,14) CE(13,15)
    CE(1,2) CE(5,6) CE(9,10) CE(13,14)
    CE(0,4) CE(1,5) CE(2,6) CE(3,7) CE(8,12) CE(9,13) CE(10,14) CE(11,15)
    CE(2,4) CE(3,5) CE(10,12) CE(11,13)
    CE(1,2) CE(3,4) CE(5,6) CE(9,10) CE(11,12) CE(13,14)
    CE(0,8) CE(1,9) CE(2,10) CE(3,11) CE(4,12) CE(5,13) CE(6,14) CE(7,15)
    CE(4,8) CE(5,9) CE(6,10) CE(7,11)
    CE(2,4) CE(3,5) CE(6,8) CE(7,9) CE(10,12) CE(11,13)
    CE(1,2) CE(3,4) CE(5,6) CE(7,8) CE(9,10) CE(11,12) CE(13,14)
}
#undef CE

// L (desc,16) <- top-16 of L ∪ c (desc,16): max-half + bitonic merge
__device__ __forceinline__ void merge_into16(u32 (&L)[16], const u32 (&c)[16]) {
#pragma unroll
    for (int i = 0; i < 16; i++) L[i] = umaxu(L[i], c[15 - i]);
#pragma unroll
    for (int j = 8; j >= 1; j >>= 1)
#pragma unroll
        for (int i = 0; i < 16; i++)
            if ((i & j) == 0) {
                int p = i | j;
                u32 a = L[i], b = L[p];
                L[i] = umaxu(a, b);
                L[p] = uminu(a, b);
            }
}

// ---------------------------------------------------------------------------
// p1: transpose x[b][c][n] -> xtf (fp32, ws), xth/xtl (bf16 hi/lo, RNE), sq.
// (validated rounds 2-9; only xtf destination moved to ws)
// ---------------------------------------------------------------------------
__global__ __launch_bounds__(256) void p1_prep(const float* __restrict__ x,
                                               float* __restrict__ xtf,
                                               u16* __restrict__ xth,
                                               u16* __restrict__ xtl,
                                               float* __restrict__ sq) {
    __shared__ float Xp[64][65];
    int tid = threadIdx.x;
    int b = blockIdx.x >> 6;
    int n0 = (blockIdx.x & 63) * 64;
    const float* xb = x + (size_t)b * (CDIM * NPTS);
    int j = tid & 63, cq = tid >> 6;
#pragma unroll
    for (int i = 0; i < 16; i++) {
        int c = cq * 16 + i;
        Xp[c][j] = xb[(size_t)c * NPTS + n0 + j];
    }
    __syncthreads();
    if (tid < 64) {
        float s = 0.f;
        for (int c = 0; c < 64; c++) { float v = Xp[c][tid]; s = fmaf(v, v, s); }
        sq[(size_t)b * NPTS + n0 + tid] = s;
    }
    int n = tid >> 2, c0 = (tid & 3) * 16;
    float vv[16];
#pragma unroll
    for (int i = 0; i < 16; i++) vv[i] = Xp[c0 + i][n];
    size_t rowb = ((size_t)b * NPTS + n0 + n) * 64 + c0;
#pragma unroll
    for (int q = 0; q < 4; q++) {
        float4 f;
        f.x = vv[4 * q]; f.y = vv[4 * q + 1]; f.z = vv[4 * q + 2]; f.w = vv[4 * q + 3];
        *(float4*)(xtf + rowb + 4 * q) = f;
    }
    u16 hb[16], lb[16];
#pragma unroll
    for (int i = 0; i < 16; i++) {
        float v = vv[i];
        u32 bv = __float_as_uint(v);
        u32 h = (bv + 0x7FFFu + ((bv >> 16) & 1u)) >> 16;    // RNE bf16
        float hf = __uint_as_float(h << 16);
        float lf = v - hf;
        u32 bl = __float_as_uint(lf);
        u32 lo = (bl + 0x7FFFu + ((bl >> 16) & 1u)) >> 16;
        hb[i] = (u16)h; lb[i] = (u16)lo;
    }
    uint4 H0, H1, L0, L1;
    H0.x = hb[0] | ((u32)hb[1] << 16);  H0.y = hb[2] | ((u32)hb[3] << 16);
    H0.z = hb[4] | ((u32)hb[5] << 16);  H0.w = hb[6] | ((u32)hb[7] << 16);
    H1.x = hb[8] | ((u32)hb[9] << 16);  H1.y = hb[10] | ((u32)hb[11] << 16);
    H1.z = hb[12] | ((u32)hb[13] << 16); H1.w = hb[14] | ((u32)hb[15] << 16);
    L0.x = lb[0] | ((u32)lb[1] << 16);  L0.y = lb[2] | ((u32)lb[3] << 16);
    L0.z = lb[4] | ((u32)lb[5] << 16);  L0.w = lb[6] | ((u32)lb[7] << 16);
    L1.x = lb[8] | ((u32)lb[9] << 16);  L1.y = lb[10] | ((u32)lb[11] << 16);
    L1.z = lb[12] | ((u32)lb[13] << 16); L1.w = lb[14] | ((u32)lb[15] << 16);
    *(uint4*)(xth + rowb) = H0;
    *(uint4*)(xth + rowb + 8) = H1;
    *(uint4*)(xtl + rowb) = L0;
    *(uint4*)(xtl + rowb + 8) = L1;
}

// ---------------------------------------------------------------------------
// k2: byte-identical to the r8-validated NCH=4 config. MFMA Gram + per-lane
// top-16/class + class merge -> chunk-top-16 full u32 keys.
// ---------------------------------------------------------------------------
__device__ __forceinline__ void stage_tile(const u16* __restrict__ srcb,
                                           char* lds, int w, int lane) {
#pragma unroll
    for (int i = 0; i < 2; i++) {
        int G = w * 128 + i * 64 + lane;
        int rr = G >> 3, gp = G & 7;
        const u16* src = srcb + rr * 64 + ((gp ^ (rr & 7)) << 3);
        char* dst = lds + (w * 128 + i * 64) * 16;
        load_lds_16(src, dst);
    }
}

__device__ __forceinline__ void sel_phase(const float16v& A, float (*Tw)[36],
                                          float pb, int colbase,
                                          int l31, int lh, u32 (&L)[16]) {
#pragma unroll
    for (int r = 0; r < 16; r++) {
        int row = (r & 3) + 8 * (r >> 2) + 4 * lh;   // m101 C/D row map
        Tw[row][l31] = fmaf(2.f, A[r], pb);          // s + 1024, always > 0
    }
    u32 c[16];
    const u32* Tu = (const u32*)&Tw[l31][16 * lh];
#pragma unroll
    for (int q = 0; q < 4; q++) {
        uint4 v = *(const uint4*)(Tu + 4 * q);
        u32 cg = (u32)(colbase + 16 * lh + 4 * q);
        c[4 * q + 0] = (v.x & 0xFFFFF000u) | (cg + 0);
        c[4 * q + 1] = (v.y & 0xFFFFF000u) | (cg + 1);
        c[4 * q + 2] = (v.z & 0xFFFFF000u) | (cg + 2);
        c[4 * q + 3] = (v.w & 0xFFFFF000u) | (cg + 3);
    }
    sort16_desc(c);
    merge_into16(L, c);
}

__global__ __launch_bounds__(256, 4) void k2_gram(const u16* __restrict__ xth,
                                                  const u16* __restrict__ xtl,
                                                  const float* __restrict__ sq,
                                                  u32* __restrict__ cand) {
    __shared__ char pool[8192];
    __shared__ float T[4][32][36];
    int tid = threadIdx.x;
    int lane = tid & 63, w = tid >> 6;
    int l31 = lane & 31, lh = lane >> 5;
    int b = blockIdx.x & 7;
    int rt = (blockIdx.x >> 3) & 31;
    int ch = blockIdx.x >> 8;
    int r0 = rt * 128;
    int cb = ch * 1024;
    size_t bbase = (size_t)b * NPTS;

    short8v Ah[4], Al[4];
    {
        const u16* pa = xth + (bbase + r0 + 32 * w + l31) * 64 + 8 * lh;
        const u16* pl = xtl + (bbase + r0 + 32 * w + l31) * 64 + 8 * lh;
#pragma unroll
        for (int s = 0; s < 4; s++) {
            Ah[s] = *(const short8v*)(pa + 16 * s);
            Al[s] = *(const short8v*)(pl + 16 * s);
        }
    }

    u32 L[16];
#pragma unroll
    for (int i = 0; i < 16; i++) L[i] = 0u;

    stage_tile(xth + (bbase + cb) * 64, pool, w, lane);
    __syncthreads();

    float (*Tw)[36] = T[w];

    for (int t = 0; t < 16; t++) {
        int n1 = cb + t * 64;
        float pb0 = 1024.f - sq[bbase + n1 + l31];
        float pb1 = 1024.f - sq[bbase + n1 + 32 + l31];

        float16v a0 = {};
#pragma unroll
        for (int s = 0; s < 4; s++) {
            int gx = 2 * s + lh;
            int sw = (gx ^ (l31 & 7)) << 4;
            short8v bh0 = *(const short8v*)(pool + l31 * 128 + sw);
            a0 = MFMA32(Ah[s], bh0, a0);
            a0 = MFMA32(Al[s], bh0, a0);
        }
        sel_phase(a0, Tw, pb0, n1, l31, lh, L);

        float16v a1 = {};
#pragma unroll
        for (int s = 0; s < 4; s++) {
            int gx = 2 * s + lh;
            int sw = (gx ^ (l31 & 7)) << 4;
            short8v bh1 = *(const short8v*)(pool + (32 + l31) * 128 + sw);
            a1 = MFMA32(Ah[s], bh1, a1);
            a1 = MFMA32(Al[s], bh1, a1);
        }
        __syncthreads();
        if (t < 15)
            stage_tile(xth + (bbase + n1 + 64) * 64, pool, w, lane);
        sel_phase(a1, Tw, pb1, n1 + 32, l31, lh, L);
        __syncthreads();
    }

    u32 M[16];
#pragma unroll
    for (int i = 0; i < 16; i++) {
        u32 pv = __shfl_xor(L[15 - i], 32);
        M[i] = umaxu(L[i], pv);
    }
#pragma unroll
    for (int j = 8; j >= 1; j >>= 1)
#pragma unroll
        for (int i = 0; i < 16; i++)
            if ((i & j) == 0) {
                int p = i | j;
                u32 a = M[i], b2 = M[p];
                M[i] = umaxu(a, b2);
                M[p] = uminu(a, b2);
            }
    if (lane < 32) {
        u32* cr = cand + (bbase + r0 + 32 * w + l31) * 64 + ch * 16;
#pragma unroll
        for (int q = 0; q < 4; q++) {
            uint4 v;
            v.x = M[4 * q]; v.y = M[4 * q + 1]; v.z = M[4 * q + 2]; v.w = M[4 * q + 3];
            *(uint4*)(cr + 4 * q) = v;
        }
    }
}

// ---------------------------------------------------------------------------
// k1: y1 only (y2 is computed on the fly in k2b3). W-transform folded in
// (was k0): Wt1[c][o] = W[o*128+c]. 256 blocks, 128n x 64o tile, acc 8x4.
// Same fp32 summation order as prior rounds -> bitwise-identical y1.
// ---------------------------------------------------------------------------
__global__ __launch_bounds__(256) void k1_prep(const float* __restrict__ x,
                                               const float* __restrict__ W,
                                               float* __restrict__ y1) {
    __shared__ float Xt[64][128];
    __shared__ float Wt[64][64];
    int tid = threadIdx.x;
    int gr0 = blockIdx.x * 128;
    int b = gr0 >> 12;
    int n0 = gr0 & 4095;
    const float* xb = x + (size_t)b * (CDIM * NPTS) + n0;

    for (int k = 0; k < 32; k++) {
        int f = tid + 256 * k;
        int c = f >> 7, j = f & 127;
        Xt[c][j] = xb[(size_t)c * NPTS + j];
    }
    for (int k = 0; k < 16; k++) {
        int f = tid + 256 * k;
        int c = f >> 6, o = f & 63;
        Wt[c][o] = W[o * 128 + c];
    }
    __syncthreads();

    int tr = tid & 15, tc = tid >> 4;      // tr: 8-row group, tc: 4-col group
    float acc[8][4];
#pragma unroll
    for (int i = 0; i < 8; i++)
#pragma unroll
        for (int j = 0; j < 4; j++) acc[i][j] = 0.f;

#pragma unroll 4
    for (int c = 0; c < 64; c++) {
        float a[8], bb[4];
        *(float4*)&a[0] = *(const float4*)&Xt[c][8 * tr];
        *(float4*)&a[4] = *(const float4*)&Xt[c][8 * tr + 4];
        *(float4*)&bb[0] = *(const float4*)&Wt[c][4 * tc];
#pragma unroll
        for (int i = 0; i < 8; i++)
#pragma unroll
            for (int j = 0; j < 4; j++) acc[i][j] = fmaf(a[i], bb[j], acc[i][j]);
    }

#pragma unroll
    for (int i = 0; i < 8; i++) {
        int r = gr0 + 8 * tr + i;
        float4 s0;
        s0.x = acc[i][0]; s0.y = acc[i][1]; s0.z = acc[i][2]; s0.w = acc[i][3];
        *(float4*)(y1 + (size_t)r * 64 + 4 * tc) = s0;
    }
}

// ---------------------------------------------------------------------------
// k2b3: FUSED rescore + top-20 + output. 8192 blocks x 256 thr; wave = row.
//   sort 64 quantized keys -> top-32 cols -> coop exact fp32 rescore (r7
//   pattern) -> exact u64 top-20 -> gather y1 rows (max) + on-the-fly
//   y2row = xr . Wt2 (Wt2 from W in LDS) + bias -> scatter-store out.
// ---------------------------------------------------------------------------
__global__ __launch_bounds__(256) void k2b3(const float* __restrict__ xtf,
                                            const float* __restrict__ sq,
                                            const u32* __restrict__ cand,
                                            const float* __restrict__ y1,
                                            const float* __restrict__ W,
                                            const float* __restrict__ bias,
                                            float* __restrict__ out) {
    __shared__ float wt2[64][64];   // (W2-W1)^T : wt2[c][o]
    __shared__ float xr[4][64];
    __shared__ float dd[4][32];
    __shared__ u32 cols[4][32];
    __shared__ int ids[4][KSEL];
    int tid = threadIdx.x;
    int lane = tid & 63, w = tid >> 6;
    int bid = blockIdx.x;
    int b = bid & 7;                       // batch == XCD slot
    int n = (bid >> 3) * 4 + w;
    size_t row = (size_t)b * NPTS + n;
    size_t bbase = (size_t)b * NPTS;

    // stage Wt2 (block-wide)
    for (int k = 0; k < 16; k++) {
        int f = tid + 256 * k;
        int c = f >> 6, o = f & 63;
        wt2[c][o] = W[o * 128 + 64 + c] - W[o * 128 + c];
    }
    if (lane < 16)
        *(float4*)&xr[w][lane * 4] = *(const float4*)(xtf + row * 64 + lane * 4);
    u32 key = cand[row * 64 + lane];
    __syncthreads();                       // wt2 ready (xr per-wave, also done)

    // bitonic sort-64 desc on quantized keys (validated r8)
#pragma unroll
    for (u32 k = 2; k <= 64; k <<= 1) {
#pragma unroll
        for (u32 j2 = k >> 1; j2 >= 1; j2 >>= 1) {
            bool up = ((lane & k) == 0);
            bool lower = ((lane & j2) == 0);
            u32 p = __shfl_xor(key, j2);
            u32 mx = (key > p) ? key : p, mn = (key > p) ? p : key;
            key = (lower == up) ? mx : mn;
        }
    }
    if (lane < 32) cols[w][lane] = key & 0xFFFu;

    // cooperative exact rescore: 2 passes x 16 candidates, 4 lanes each
    int s = lane & 3, g = lane >> 2;
    float4 xq[4];
#pragma unroll
    for (int q = 0; q < 4; q++) xq[q] = *(const float4*)&xr[w][16 * q + 4 * s];

#pragma unroll
    for (int p = 0; p < 2; p++) {
        int m = cols[w][p * 16 + g];
        const float* pm = xtf + (bbase + m) * 64;
        float d = 0.f;
#pragma unroll
        for (int q = 0; q < 4; q++) {
            float4 v = *(const float4*)(pm + 16 * q + 4 * s);
            d = fmaf(v.x, xq[q].x, d); d = fmaf(v.y, xq[q].y, d);
            d = fmaf(v.z, xq[q].z, d); d = fmaf(v.w, xq[q].w, d);
        }
        d += __shfl_xor(d, 1);
        d += __shfl_xor(d, 2);
        if (s == 0) dd[w][p * 16 + g] = d;
    }

    // exact u64 keys + top-20 (validated r8)
    u64 kE = 0;
    if (lane < 32) {
        int m = (int)cols[w][lane];
        float sE = fmaf(2.f, dd[w][lane], -sq[bbase + m]);
        kE = ((u64)ordf(sE) << 32) | (u32)(~(u32)m);
    }
#pragma unroll
    for (u32 k = 2; k <= 64; k <<= 1) {
#pragma unroll
        for (u32 j2 = k >> 1; j2 >= 1; j2 >>= 1) {
            bool up = ((lane & k) == 0);
            bool lower = ((lane & j2) == 0);
            u64 p = __shfl_xor(kE, j2);
            u64 mx = (kE > p) ? kE : p, mn = (kE > p) ? p : kE;
            kE = (lower == up) ? mx : mn;
        }
    }
    if (lane < KSEL) ids[w][lane] = (int)(~(u32)kE);

    // ---- output: out[b][o=lane][n] = max_k y1[m_k][o] + xr.wt2[:,o] + bias[o]
    const float* y1b = y1 + bbase * 64;
    float acc = -FLT_MAX;
#pragma unroll
    for (int k = 0; k < KSEL; k++) {
        int m = ids[w][k];                 // wave-uniform broadcast
        acc = fmaxf(acc, y1b[(size_t)m * 64 + lane]);
    }
    float acc2 = 0.f;
#pragma unroll 8
    for (int c = 0; c < 64; c++)
        acc2 = fmaf(xr[w][c], wt2[c][lane], acc2);
    out[((size_t)(b * 64 + lane)) * NPTS + n] = acc + acc2 + bias[lane];
}

// ---------------------------------------------------------------------------
extern "C" void kernel_launch(void* const* d_in, const int* in_sizes, int n_in,
                              void* d_out, int out_size, void* d_ws, size_t ws_size,
                              hipStream_t stream) {
    const float* x    = (const float*)d_in[0];   // (8, 64, 4096)
    const float* W    = (const float*)d_in[1];   // (64, 128)
    const float* bias = (const float*)d_in[2];   // (64,)
    float* out = (float*)d_out;                  // (8, 64, 4096)
    float* ws = (float*)d_ws;

    u16* xth   = (u16*)ws;                  // [0,4MB)   dies after k2
    u16* xtl   = (u16*)(ws + F_XTL);        // [4,8MB)   dies after k2
    u32* candb = (u32*)(ws + F_CAND);       // [8,16MB)
    float* xtf = ws + F_XTF;                // [16,24MB)
    float* sq  = ws + F_SQ;                 // [24MB, +128KB)
    float* y1  = ws;                        // overlays xth/xtl after k2

    hipLaunchKernelGGL(p1_prep, dim3(512),  dim3(256), 0, stream, x, xtf, xth, xtl, sq);
    hipLaunchKernelGGL(k2_gram, dim3(1024), dim3(256), 0, stream, xth, xtl, sq, candb);
    hipLaunchKernelGGL(k1_prep, dim3(256),  dim3(256), 0, stream, x, W, y1);
    hipLaunchKernelGGL(k2b3,    dim3(8192), dim3(256), 0, stream, xtf, sq, candb, y1, W, bias, out);
}

// Round 11
// 153.838 us; speedup vs baseline: 1.6130x; 1.6130x over previous
//
#include <hip/hip_runtime.h>
#include <float.h>

typedef unsigned long long u64;
typedef unsigned int u32;
typedef unsigned short u16;

#define NPTS 4096
#define CDIM 64
#define BATCH 8
#define KSEL 20

// ws layout in float-slots (total ~24.3 MB; r9 proved ws >= 26.6 MB):
//   [0, 1M)   xth (2M u16)         -> y1 overlays [0,2M) after k2
//   [1M, 2M)  xtl (2M u16)
//   [2M, 4M)  cand (2M u32)
//   [4M, 6M)  xtf (fp32 points)
//   [6M, +32K) sq
//   [6M+32K, +4K) wt2g ((W2-W1)^T, [c][o])
#define F_XTL (BATCH * NPTS * 32)               // 1M
#define F_CAND (2 * BATCH * NPTS * 32)          // 2M
#define F_XTF (4 * BATCH * NPTS * 32)           // 4M
#define F_SQ (6 * BATCH * NPTS * 32)            // 6M
#define F_WT2 (F_SQ + BATCH * NPTS)             // 6M + 32K

typedef __attribute__((ext_vector_type(8))) short short8v;   // 8 bf16 (4 VGPR)
typedef __attribute__((ext_vector_type(16))) float float16v; // MFMA 32x32 acc

#define MFMA32(a, b, c) __builtin_amdgcn_mfma_f32_32x32x16_bf16(a, b, c, 0, 0, 0)

__device__ __forceinline__ u32 ordf(float f) {
    u32 u = __float_as_uint(f);
    return (u >> 31) ? ~u : (u | 0x80000000u);
}
__device__ __forceinline__ u32 umaxu(u32 a, u32 b) { return a > b ? a : b; }
__device__ __forceinline__ u32 uminu(u32 a, u32 b) { return a < b ? a : b; }

__device__ __forceinline__ void load_lds_16(const void* g, void* l) {
    __builtin_amdgcn_global_load_lds(
        (const __attribute__((address_space(1))) unsigned int*)g,
        (__attribute__((address_space(3))) unsigned int*)l, 16, 0, 0);
}

#define CE(i, j) { u32 a_ = c[i], b_ = c[j]; c[i] = umaxu(a_, b_); c[j] = uminu(a_, b_); }

// Batcher odd-even merge sort, 16 u32 keys, descending. 63 CEs. (validated r7-r10)
__device__ __forceinline__ void sort16_desc(u32 (&c)[16]) {
    CE(0,1) CE(2,3) CE(4,5) CE(6,7) CE(8,9) CE(10,11) CE(12,13) CE(14,15)
    CE(0,2) CE(1,3) CE(4,6) CE(5,7) CE(8,10) CE(9,11) CE(12,14) CE(13,15)
    CE(1,2) CE(5,6) CE(9,10) CE(13,14)
    CE(0,4) CE(1,5) CE(2,6) CE(3,7) CE(8,12) CE(9,13) CE(10,14) CE(11,15)
    CE(2,4) CE(3,5) CE(10,12) CE(11,13)
    CE(1,2) CE(3,4) CE(5,6) CE(9,10) CE(11,12) CE(13,14)
    CE(0,8) CE(1,9) CE(2,10) CE(3,11) CE(4,12) CE(5,13) CE(6,14) CE(7,15)
    CE(4,8) CE(5,9) CE(6,10) CE(7,11)
    CE(2,4) CE(3,5) CE(6,8) CE(7,9) CE(10,12) CE(11,13)
    CE(1,2) CE(3,4) CE(5,6) CE(7,8) CE(9,10) CE(11,12) CE(13,14)
}
#undef CE

// L (desc,16) <- top-16 of L ∪ c (desc,16): max-half + bitonic merge
__device__ __forceinline__ void merge_into16(u32 (&L)[16], const u32 (&c)[16]) {
#pragma unroll
    for (int i = 0; i < 16; i++) L[i] = umaxu(L[i], c[15 - i]);
#pragma unroll
    for (int j = 8; j >= 1; j >>= 1)
#pragma unroll
        for (int i = 0; i < 16; i++)
            if ((i & j) == 0) {
                int p = i | j;
                u32 a = L[i], b = L[p];
                L[i] = umaxu(a, b);
                L[p] = uminu(a, b);
            }
}

// ---------------------------------------------------------------------------
// k0: wt2g[c*64+o] = W[o*128+64+c] - W[o*128+c]  (bad stride paid ONCE)
// ---------------------------------------------------------------------------
__global__ void k0_wt2(const float* __restrict__ W, float* __restrict__ wt2g) {
    int f = blockIdx.x * 256 + threadIdx.x;
    if (f >= 64 * 64) return;
    int c = f >> 6, o = f & 63;
    wt2g[f] = W[o * 128 + 64 + c] - W[o * 128 + c];
}

// ---------------------------------------------------------------------------
// p1: transpose x[b][c][n] -> xtf (fp32, ws), xth/xtl (bf16 hi/lo, RNE), sq.
// (validated rounds 2-10)
// ---------------------------------------------------------------------------
__global__ __launch_bounds__(256) void p1_prep(const float* __restrict__ x,
                                               float* __restrict__ xtf,
                                               u16* __restrict__ xth,
                                               u16* __restrict__ xtl,
                                               float* __restrict__ sq) {
    __shared__ float Xp[64][65];
    int tid = threadIdx.x;
    int b = blockIdx.x >> 6;
    int n0 = (blockIdx.x & 63) * 64;
    const float* xb = x + (size_t)b * (CDIM * NPTS);
    int j = tid & 63, cq = tid >> 6;
#pragma unroll
    for (int i = 0; i < 16; i++) {
        int c = cq * 16 + i;
        Xp[c][j] = xb[(size_t)c * NPTS + n0 + j];
    }
    __syncthreads();
    if (tid < 64) {
        float s = 0.f;
        for (int c = 0; c < 64; c++) { float v = Xp[c][tid]; s = fmaf(v, v, s); }
        sq[(size_t)b * NPTS + n0 + tid] = s;
    }
    int n = tid >> 2, c0 = (tid & 3) * 16;
    float vv[16];
#pragma unroll
    for (int i = 0; i < 16; i++) vv[i] = Xp[c0 + i][n];
    size_t rowb = ((size_t)b * NPTS + n0 + n) * 64 + c0;
#pragma unroll
    for (int q = 0; q < 4; q++) {
        float4 f;
        f.x = vv[4 * q]; f.y = vv[4 * q + 1]; f.z = vv[4 * q + 2]; f.w = vv[4 * q + 3];
        *(float4*)(xtf + rowb + 4 * q) = f;
    }
    u16 hb[16], lb[16];
#pragma unroll
    for (int i = 0; i < 16; i++) {
        float v = vv[i];
        u32 bv = __float_as_uint(v);
        u32 h = (bv + 0x7FFFu + ((bv >> 16) & 1u)) >> 16;    // RNE bf16
        float hf = __uint_as_float(h << 16);
        float lf = v - hf;
        u32 bl = __float_as_uint(lf);
        u32 lo = (bl + 0x7FFFu + ((bl >> 16) & 1u)) >> 16;
        hb[i] = (u16)h; lb[i] = (u16)lo;
    }
    uint4 H0, H1, L0, L1;
    H0.x = hb[0] | ((u32)hb[1] << 16);  H0.y = hb[2] | ((u32)hb[3] << 16);
    H0.z = hb[4] | ((u32)hb[5] << 16);  H0.w = hb[6] | ((u32)hb[7] << 16);
    H1.x = hb[8] | ((u32)hb[9] << 16);  H1.y = hb[10] | ((u32)hb[11] << 16);
    H1.z = hb[12] | ((u32)hb[13] << 16); H1.w = hb[14] | ((u32)hb[15] << 16);
    L0.x = lb[0] | ((u32)lb[1] << 16);  L0.y = lb[2] | ((u32)lb[3] << 16);
    L0.z = lb[4] | ((u32)lb[5] << 16);  L0.w = lb[6] | ((u32)lb[7] << 16);
    L1.x = lb[8] | ((u32)lb[9] << 16);  L1.y = lb[10] | ((u32)lb[11] << 16);
    L1.z = lb[12] | ((u32)lb[13] << 16); L1.w = lb[14] | ((u32)lb[15] << 16);
    *(uint4*)(xth + rowb) = H0;
    *(uint4*)(xth + rowb + 8) = H1;
    *(uint4*)(xtl + rowb) = L0;
    *(uint4*)(xtl + rowb + 8) = L1;
}

// ---------------------------------------------------------------------------
// k2: byte-identical to the r8-validated NCH=4 config. MFMA Gram + per-lane
// top-16/class + class merge -> chunk-top-16 full u32 keys.
// ---------------------------------------------------------------------------
__device__ __forceinline__ void stage_tile(const u16* __restrict__ srcb,
                                           char* lds, int w, int lane) {
#pragma unroll
    for (int i = 0; i < 2; i++) {
        int G = w * 128 + i * 64 + lane;
        int rr = G >> 3, gp = G & 7;
        const u16* src = srcb + rr * 64 + ((gp ^ (rr & 7)) << 3);
        char* dst = lds + (w * 128 + i * 64) * 16;
        load_lds_16(src, dst);
    }
}

__device__ __forceinline__ void sel_phase(const float16v& A, float (*Tw)[36],
                                          float pb, int colbase,
                                          int l31, int lh, u32 (&L)[16]) {
#pragma unroll
    for (int r = 0; r < 16; r++) {
        int row = (r & 3) + 8 * (r >> 2) + 4 * lh;   // m101 C/D row map
        Tw[row][l31] = fmaf(2.f, A[r], pb);          // s + 1024, always > 0
    }
    u32 c[16];
    const u32* Tu = (const u32*)&Tw[l31][16 * lh];
#pragma unroll
    for (int q = 0; q < 4; q++) {
        uint4 v = *(const uint4*)(Tu + 4 * q);
        u32 cg = (u32)(colbase + 16 * lh + 4 * q);
        c[4 * q + 0] = (v.x & 0xFFFFF000u) | (cg + 0);
        c[4 * q + 1] = (v.y & 0xFFFFF000u) | (cg + 1);
        c[4 * q + 2] = (v.z & 0xFFFFF000u) | (cg + 2);
        c[4 * q + 3] = (v.w & 0xFFFFF000u) | (cg + 3);
    }
    sort16_desc(c);
    merge_into16(L, c);
}

__global__ __launch_bounds__(256, 4) void k2_gram(const u16* __restrict__ xth,
                                                  const u16* __restrict__ xtl,
                                                  const float* __restrict__ sq,
                                                  u32* __restrict__ cand) {
    __shared__ char pool[8192];
    __shared__ float T[4][32][36];
    int tid = threadIdx.x;
    int lane = tid & 63, w = tid >> 6;
    int l31 = lane & 31, lh = lane >> 5;
    int b = blockIdx.x & 7;
    int rt = (blockIdx.x >> 3) & 31;
    int ch = blockIdx.x >> 8;
    int r0 = rt * 128;
    int cb = ch * 1024;
    size_t bbase = (size_t)b * NPTS;

    short8v Ah[4], Al[4];
    {
        const u16* pa = xth + (bbase + r0 + 32 * w + l31) * 64 + 8 * lh;
        const u16* pl = xtl + (bbase + r0 + 32 * w + l31) * 64 + 8 * lh;
#pragma unroll
        for (int s = 0; s < 4; s++) {
            Ah[s] = *(const short8v*)(pa + 16 * s);
            Al[s] = *(const short8v*)(pl + 16 * s);
        }
    }

    u32 L[16];
#pragma unroll
    for (int i = 0; i < 16; i++) L[i] = 0u;

    stage_tile(xth + (bbase + cb) * 64, pool, w, lane);
    __syncthreads();

    float (*Tw)[36] = T[w];

    for (int t = 0; t < 16; t++) {
        int n1 = cb + t * 64;
        float pb0 = 1024.f - sq[bbase + n1 + l31];
        float pb1 = 1024.f - sq[bbase + n1 + 32 + l31];

        float16v a0 = {};
#pragma unroll
        for (int s = 0; s < 4; s++) {
            int gx = 2 * s + lh;
            int sw = (gx ^ (l31 & 7)) << 4;
            short8v bh0 = *(const short8v*)(pool + l31 * 128 + sw);
            a0 = MFMA32(Ah[s], bh0, a0);
            a0 = MFMA32(Al[s], bh0, a0);
        }
        sel_phase(a0, Tw, pb0, n1, l31, lh, L);

        float16v a1 = {};
#pragma unroll
        for (int s = 0; s < 4; s++) {
            int gx = 2 * s + lh;
            int sw = (gx ^ (l31 & 7)) << 4;
            short8v bh1 = *(const short8v*)(pool + (32 + l31) * 128 + sw);
            a1 = MFMA32(Ah[s], bh1, a1);
            a1 = MFMA32(Al[s], bh1, a1);
        }
        __syncthreads();
        if (t < 15)
            stage_tile(xth + (bbase + n1 + 64) * 64, pool, w, lane);
        sel_phase(a1, Tw, pb1, n1 + 32, l31, lh, L);
        __syncthreads();
    }

    u32 M[16];
#pragma unroll
    for (int i = 0; i < 16; i++) {
        u32 pv = __shfl_xor(L[15 - i], 32);
        M[i] = umaxu(L[i], pv);
    }
#pragma unroll
    for (int j = 8; j >= 1; j >>= 1)
#pragma unroll
        for (int i = 0; i < 16; i++)
            if ((i & j) == 0) {
                int p = i | j;
                u32 a = M[i], b2 = M[p];
                M[i] = umaxu(a, b2);
                M[p] = uminu(a, b2);
            }
    if (lane < 32) {
        u32* cr = cand + (bbase + r0 + 32 * w + l31) * 64 + ch * 16;
#pragma unroll
        for (int q = 0; q < 4; q++) {
            uint4 v;
            v.x = M[4 * q]; v.y = M[4 * q + 1]; v.z = M[4 * q + 2]; v.w = M[4 * q + 3];
            *(uint4*)(cr + 4 * q) = v;
        }
    }
}

// ---------------------------------------------------------------------------
// k1: y1 only; Wt1 staged from W (256 blocks -> bad-stride cost negligible).
// Same fp32 summation order as prior rounds -> bitwise-identical y1.
// ---------------------------------------------------------------------------
__global__ __launch_bounds__(256) void k1_prep(const float* __restrict__ x,
                                               const float* __restrict__ W,
                                               float* __restrict__ y1) {
    __shared__ float Xt[64][128];
    __shared__ float Wt[64][64];
    int tid = threadIdx.x;
    int gr0 = blockIdx.x * 128;
    int b = gr0 >> 12;
    int n0 = gr0 & 4095;
    const float* xb = x + (size_t)b * (CDIM * NPTS) + n0;

    for (int k = 0; k < 32; k++) {
        int f = tid + 256 * k;
        int c = f >> 7, j = f & 127;
        Xt[c][j] = xb[(size_t)c * NPTS + j];
    }
    for (int k = 0; k < 16; k++) {
        int f = tid + 256 * k;
        int c = f >> 6, o = f & 63;
        Wt[c][o] = W[o * 128 + c];
    }
    __syncthreads();

    int tr = tid & 15, tc = tid >> 4;
    float acc[8][4];
#pragma unroll
    for (int i = 0; i < 8; i++)
#pragma unroll
        for (int j = 0; j < 4; j++) acc[i][j] = 0.f;

#pragma unroll 4
    for (int c = 0; c < 64; c++) {
        float a[8], bb[4];
        *(float4*)&a[0] = *(const float4*)&Xt[c][8 * tr];
        *(float4*)&a[4] = *(const float4*)&Xt[c][8 * tr + 4];
        *(float4*)&bb[0] = *(const float4*)&Wt[c][4 * tc];
#pragma unroll
        for (int i = 0; i < 8; i++)
#pragma unroll
            for (int j = 0; j < 4; j++) acc[i][j] = fmaf(a[i], bb[j], acc[i][j]);
    }

#pragma unroll
    for (int i = 0; i < 8; i++) {
        int r = gr0 + 8 * tr + i;
        float4 s0;
        s0.x = acc[i][0]; s0.y = acc[i][1]; s0.z = acc[i][2]; s0.w = acc[i][3];
        *(float4*)(y1 + (size_t)r * 64 + 4 * tc) = s0;
    }
}

// ---------------------------------------------------------------------------
// k2b3: FUSED rescore + top-20 + output. 8192 blocks x 256 thr; wave = row.
//   wt2 staged COALESCED from precomputed wt2g (r10 fix); output transposed
//   through LDS for float4 (16B/line) stores.
// ---------------------------------------------------------------------------
__global__ __launch_bounds__(256) void k2b3(const float* __restrict__ xtf,
                                            const float* __restrict__ sq,
                                            const u32* __restrict__ cand,
                                            const float* __restrict__ y1,
                                            const float* __restrict__ wt2g,
                                            const float* __restrict__ bias,
                                            float* __restrict__ out) {
    __shared__ float wt2[64][64];   // (W2-W1)^T : wt2[c][o]
    __shared__ float xr[4][64];
    __shared__ float dd[4][32];
    __shared__ u32 cols[4][32];
    __shared__ int ids[4][KSEL];
    __shared__ float outT[64][5];   // [o][n-local], pad 5 (2-way banks = free)
    int tid = threadIdx.x;
    int lane = tid & 63, w = tid >> 6;
    int bid = blockIdx.x;
    int b = bid & 7;                       // batch == XCD slot
    int n0 = (bid >> 3) * 4;
    int n = n0 + w;
    size_t row = (size_t)b * NPTS + n;
    size_t bbase = (size_t)b * NPTS;

    // stage wt2 coalesced (16 KB as 1024 float4s)
#pragma unroll
    for (int k = 0; k < 4; k++) {
        int f = tid + 256 * k;
        ((float4*)wt2)[f] = ((const float4*)wt2g)[f];
    }
    if (lane < 16)
        *(float4*)&xr[w][lane * 4] = *(const float4*)(xtf + row * 64 + lane * 4);
    u32 key = cand[row * 64 + lane];
    __syncthreads();                       // wt2 + xr ready

    // bitonic sort-64 desc on quantized keys (validated r8-r10)
#pragma unroll
    for (u32 k = 2; k <= 64; k <<= 1) {
#pragma unroll
        for (u32 j2 = k >> 1; j2 >= 1; j2 >>= 1) {
            bool up = ((lane & k) == 0);
            bool lower = ((lane & j2) == 0);
            u32 p = __shfl_xor(key, j2);
            u32 mx = (key > p) ? key : p, mn = (key > p) ? p : key;
            key = (lower == up) ? mx : mn;
        }
    }
    if (lane < 32) cols[w][lane] = key & 0xFFFu;

    // cooperative exact rescore: 2 passes x 16 candidates, 4 lanes each
    int s = lane & 3, g = lane >> 2;
    float4 xq[4];
#pragma unroll
    for (int q = 0; q < 4; q++) xq[q] = *(const float4*)&xr[w][16 * q + 4 * s];

#pragma unroll
    for (int p = 0; p < 2; p++) {
        int m = cols[w][p * 16 + g];
        const float* pm = xtf + (bbase + m) * 64;
        float d = 0.f;
#pragma unroll
        for (int q = 0; q < 4; q++) {
            float4 v = *(const float4*)(pm + 16 * q + 4 * s);
            d = fmaf(v.x, xq[q].x, d); d = fmaf(v.y, xq[q].y, d);
            d = fmaf(v.z, xq[q].z, d); d = fmaf(v.w, xq[q].w, d);
        }
        d += __shfl_xor(d, 1);
        d += __shfl_xor(d, 2);
        if (s == 0) dd[w][p * 16 + g] = d;
    }

    // exact u64 keys + top-20 (validated r8-r10)
    u64 kE = 0;
    if (lane < 32) {
        int m = (int)cols[w][lane];
        float sE = fmaf(2.f, dd[w][lane], -sq[bbase + m]);
        kE = ((u64)ordf(sE) << 32) | (u32)(~(u32)m);
    }
#pragma unroll
    for (u32 k = 2; k <= 64; k <<= 1) {
#pragma unroll
        for (u32 j2 = k >> 1; j2 >= 1; j2 >>= 1) {
            bool up = ((lane & k) == 0);
            bool lower = ((lane & j2) == 0);
            u64 p = __shfl_xor(kE, j2);
            u64 mx = (kE > p) ? kE : p, mn = (kE > p) ? p : kE;
            kE = (lower == up) ? mx : mn;
        }
    }
    if (lane < KSEL) ids[w][lane] = (int)(~(u32)kE);

    // ---- output: outT[o][w] = max_k y1[m_k][o] + xr.wt2[:,o]
    const float* y1b = y1 + bbase * 64;
    float acc = -FLT_MAX;
#pragma unroll
    for (int k = 0; k < KSEL; k++) {
        int m = ids[w][k];                 // wave-uniform broadcast
        acc = fmaxf(acc, y1b[(size_t)m * 64 + lane]);
    }
    float acc2 = 0.f;
#pragma unroll 8
    for (int c = 0; c < 64; c++)
        acc2 = fmaf(xr[w][c], wt2[c][lane], acc2);
    outT[lane][w] = acc + acc2 + bias[lane];
    __syncthreads();

    if (tid < 64) {
        float4 v;
        v.x = outT[tid][0]; v.y = outT[tid][1];
        v.z = outT[tid][2]; v.w = outT[tid][3];
        *(float4*)(out + ((size_t)(b * 64 + tid)) * NPTS + n0) = v;
    }
}

// ---------------------------------------------------------------------------
extern "C" void kernel_launch(void* const* d_in, const int* in_sizes, int n_in,
                              void* d_out, int out_size, void* d_ws, size_t ws_size,
                              hipStream_t stream) {
    const float* x    = (const float*)d_in[0];   // (8, 64, 4096)
    const float* W    = (const float*)d_in[1];   // (64, 128)
    const float* bias = (const float*)d_in[2];   // (64,)
    float* out = (float*)d_out;                  // (8, 64, 4096)
    float* ws = (float*)d_ws;

    u16* xth   = (u16*)ws;                  // [0,4MB)   dies after k2
    u16* xtl   = (u16*)(ws + F_XTL);        // [4,8MB)   dies after k2
    u32* candb = (u32*)(ws + F_CAND);       // [8,16MB)
    float* xtf = ws + F_XTF;                // [16,24MB)
    float* sq  = ws + F_SQ;                 // [24MB, +128KB)
    float* wt2g = ws + F_WT2;               // [+128KB, +16KB)
    float* y1  = ws;                        // overlays xth/xtl after k2

    hipLaunchKernelGGL(k0_wt2,  dim3(16),   dim3(256), 0, stream, W, wt2g);
    hipLaunchKernelGGL(p1_prep, dim3(512),  dim3(256), 0, stream, x, xtf, xth, xtl, sq);
    hipLaunchKernelGGL(k2_gram, dim3(1024), dim3(256), 0, stream, xth, xtl, sq, candb);
    hipLaunchKernelGGL(k1_prep, dim3(256),  dim3(256), 0, stream, x, W, y1);
    hipLaunchKernelGGL(k2b3,    dim3(8192), dim3(256), 0, stream, xtf, sq, candb, y1, wt2g, bias, out);
}

// Round 12
// 150.992 us; speedup vs baseline: 1.6434x; 1.0188x over previous
//
#include <hip/hip_runtime.h>
#include <float.h>

typedef unsigned long long u64;
typedef unsigned int u32;
typedef unsigned short u16;

#define NPTS 4096
#define CDIM 64
#define BATCH 8
#define KSEL 20

// ws layout in float-slots (total ~24.3 MB; r9 proved ws >= 26.6 MB):
#define F_XTL (BATCH * NPTS * 32)               // 1M
#define F_CAND (2 * BATCH * NPTS * 32)          // 2M
#define F_XTF (4 * BATCH * NPTS * 32)           // 4M
#define F_SQ (6 * BATCH * NPTS * 32)            // 6M
#define F_WT2 (F_SQ + BATCH * NPTS)             // 6M + 32K

typedef __attribute__((ext_vector_type(8))) short short8v;   // 8 bf16 (4 VGPR)
typedef __attribute__((ext_vector_type(16))) float float16v; // MFMA 32x32 acc

#define MFMA32(a, b, c) __builtin_amdgcn_mfma_f32_32x32x16_bf16(a, b, c, 0, 0, 0)

__device__ __forceinline__ u32 ordf(float f) {
    u32 u = __float_as_uint(f);
    return (u >> 31) ? ~u : (u | 0x80000000u);
}
__device__ __forceinline__ u32 umaxu(u32 a, u32 b) { return a > b ? a : b; }
__device__ __forceinline__ u32 uminu(u32 a, u32 b) { return a < b ? a : b; }

__device__ __forceinline__ void load_lds_16(const void* g, void* l) {
    __builtin_amdgcn_global_load_lds(
        (const __attribute__((address_space(1))) unsigned int*)g,
        (__attribute__((address_space(3))) unsigned int*)l, 16, 0, 0);
}

#define CE(i, j) { u32 a_ = c[i], b_ = c[j]; c[i] = umaxu(a_, b_); c[j] = uminu(a_, b_); }

// Batcher odd-even merge sort, 16 u32 keys, descending. 63 CEs. (validated r7-r11)
__device__ __forceinline__ void sort16_desc(u32 (&c)[16]) {
    CE(0,1) CE(2,3) CE(4,5) CE(6,7) CE(8,9) CE(10,11) CE(12,13) CE(14,15)
    CE(0,2) CE(1,3) CE(4,6) CE(5,7) CE(8,10) CE(9,11) CE(12,14) CE(13,15)
    CE(1,2) CE(5,6) CE(9,10) CE(13,14)
    CE(0,4) CE(1,5) CE(2,6) CE(3,7) CE(8,12) CE(9,13) CE(10,14) CE(11,15)
    CE(2,4) CE(3,5) CE(10,12) CE(11,13)
    CE(1,2) CE(3,4) CE(5,6) CE(9,10) CE(11,12) CE(13,14)
    CE(0,8) CE(1,9) CE(2,10) CE(3,11) CE(4,12) CE(5,13) CE(6,14) CE(7,15)
    CE(4,8) CE(5,9) CE(6,10) CE(7,11)
    CE(2,4) CE(3,5) CE(6,8) CE(7,9) CE(10,12) CE(11,13)
    CE(1,2) CE(3,4) CE(5,6) CE(7,8) CE(9,10) CE(11,12) CE(13,14)
}
#undef CE

// L (desc,16) <- top-16 of L ∪ c (desc,16): max-half + bitonic merge
__device__ __forceinline__ void merge_into16(u32 (&L)[16], const u32 (&c)[16]) {
#pragma unroll
    for (int i = 0; i < 16; i++) L[i] = umaxu(L[i], c[15 - i]);
#pragma unroll
    for (int j = 8; j >= 1; j >>= 1)
#pragma unroll
        for (int i = 0; i < 16; i++)
            if ((i & j) == 0) {
                int p = i | j;
                u32 a = L[i], b = L[p];
                L[i] = umaxu(a, b);
                L[p] = uminu(a, b);
            }
}

// ---------------------------------------------------------------------------
// k0: wt2g[c*64+o] = W[o*128+64+c] - W[o*128+c]  (bad stride paid ONCE)
// ---------------------------------------------------------------------------
__global__ void k0_wt2(const float* __restrict__ W, float* __restrict__ wt2g) {
    int f = blockIdx.x * 256 + threadIdx.x;
    if (f >= 64 * 64) return;
    int c = f >> 6, o = f & 63;
    wt2g[f] = W[o * 128 + 64 + c] - W[o * 128 + c];
}

// ---------------------------------------------------------------------------
// p1: transpose x[b][c][n] -> xtf (fp32, ws), xth/xtl (bf16 hi/lo, RNE), sq.
// (validated rounds 2-11)
// ---------------------------------------------------------------------------
__global__ __launch_bounds__(256) void p1_prep(const float* __restrict__ x,
                                               float* __restrict__ xtf,
                                               u16* __restrict__ xth,
                                               u16* __restrict__ xtl,
                                               float* __restrict__ sq) {
    __shared__ float Xp[64][65];
    int tid = threadIdx.x;
    int b = blockIdx.x >> 6;
    int n0 = (blockIdx.x & 63) * 64;
    const float* xb = x + (size_t)b * (CDIM * NPTS);
    int j = tid & 63, cq = tid >> 6;
#pragma unroll
    for (int i = 0; i < 16; i++) {
        int c = cq * 16 + i;
        Xp[c][j] = xb[(size_t)c * NPTS + n0 + j];
    }
    __syncthreads();
    if (tid < 64) {
        float s = 0.f;
        for (int c = 0; c < 64; c++) { float v = Xp[c][tid]; s = fmaf(v, v, s); }
        sq[(size_t)b * NPTS + n0 + tid] = s;
    }
    int n = tid >> 2, c0 = (tid & 3) * 16;
    float vv[16];
#pragma unroll
    for (int i = 0; i < 16; i++) vv[i] = Xp[c0 + i][n];
    size_t rowb = ((size_t)b * NPTS + n0 + n) * 64 + c0;
#pragma unroll
    for (int q = 0; q < 4; q++) {
        float4 f;
        f.x = vv[4 * q]; f.y = vv[4 * q + 1]; f.z = vv[4 * q + 2]; f.w = vv[4 * q + 3];
        *(float4*)(xtf + rowb + 4 * q) = f;
    }
    u16 hb[16], lb[16];
#pragma unroll
    for (int i = 0; i < 16; i++) {
        float v = vv[i];
        u32 bv = __float_as_uint(v);
        u32 h = (bv + 0x7FFFu + ((bv >> 16) & 1u)) >> 16;    // RNE bf16
        float hf = __uint_as_float(h << 16);
        float lf = v - hf;
        u32 bl = __float_as_uint(lf);
        u32 lo = (bl + 0x7FFFu + ((bl >> 16) & 1u)) >> 16;
        hb[i] = (u16)h; lb[i] = (u16)lo;
    }
    uint4 H0, H1, L0, L1;
    H0.x = hb[0] | ((u32)hb[1] << 16);  H0.y = hb[2] | ((u32)hb[3] << 16);
    H0.z = hb[4] | ((u32)hb[5] << 16);  H0.w = hb[6] | ((u32)hb[7] << 16);
    H1.x = hb[8] | ((u32)hb[9] << 16);  H1.y = hb[10] | ((u32)hb[11] << 16);
    H1.z = hb[12] | ((u32)hb[13] << 16); H1.w = hb[14] | ((u32)hb[15] << 16);
    L0.x = lb[0] | ((u32)lb[1] << 16);  L0.y = lb[2] | ((u32)lb[3] << 16);
    L0.z = lb[4] | ((u32)lb[5] << 16);  L0.w = lb[6] | ((u32)lb[7] << 16);
    L1.x = lb[8] | ((u32)lb[9] << 16);  L1.y = lb[10] | ((u32)lb[11] << 16);
    L1.z = lb[12] | ((u32)lb[13] << 16); L1.w = lb[14] | ((u32)lb[15] << 16);
    *(uint4*)(xth + rowb) = H0;
    *(uint4*)(xth + rowb + 8) = H1;
    *(uint4*)(xtl + rowb) = L0;
    *(uint4*)(xtl + rowb + 8) = L1;
}

// ---------------------------------------------------------------------------
// k2: SWAPPED-operand MFMA Gram: acc = mfma(colPts, rowPts) so lane&31 = Gram
// ROW -> per-lane acc regs ARE a row-slice of 16 cols. No LDS transpose.
// Per lane: col-set {(r&3)+8(r>>2)+4*lh} (class = col bit2); key-build direct
// from regs; top-16/class; epilogue merges classes -> chunk-top-16 u32 keys.
// Grid 1024 = 8b x 32 rowtiles x 4 chunks; 256 thr (4 waves). LDS 8.2 KB.
// ---------------------------------------------------------------------------
__device__ __forceinline__ void stage_tile(const u16* __restrict__ srcb,
                                           char* lds, int w, int lane) {
#pragma unroll
    for (int i = 0; i < 2; i++) {
        int G = w * 128 + i * 64 + lane;
        int rr = G >> 3, gp = G & 7;
        const u16* src = srcb + rr * 64 + ((gp ^ (rr & 7)) << 3);
        char* dst = lds + (w * 128 + i * 64) * 16;
        load_lds_16(src, dst);
    }
}

// one 32-col half: keys straight from acc regs (no transpose).
// col(r) = colbase + 4*lh + (r&3) + 8*(r>>2); sq loaded as 4 aligned float4.
__device__ __forceinline__ void sel_half(const float16v& A,
                                         const float* __restrict__ sqp, // sq+bbase+n1(+32)
                                         int colbase, int lh, u32 (&L)[16]) {
    u32 c[16];
#pragma unroll
    for (int q = 0; q < 4; q++) {
        float4 sv = *(const float4*)(sqp + 4 * lh + 8 * q);
        float s0 = fmaf(2.f, A[4 * q + 0], 1024.f - sv.x);   // s + 1024 > 0
        float s1 = fmaf(2.f, A[4 * q + 1], 1024.f - sv.y);
        float s2 = fmaf(2.f, A[4 * q + 2], 1024.f - sv.z);
        float s3 = fmaf(2.f, A[4 * q + 3], 1024.f - sv.w);
        u32 cg = (u32)(colbase + 4 * lh + 8 * q);
        c[4 * q + 0] = (__float_as_uint(s0) & 0xFFFFF000u) | (cg + 0);
        c[4 * q + 1] = (__float_as_uint(s1) & 0xFFFFF000u) | (cg + 1);
        c[4 * q + 2] = (__float_as_uint(s2) & 0xFFFFF000u) | (cg + 2);
        c[4 * q + 3] = (__float_as_uint(s3) & 0xFFFFF000u) | (cg + 3);
    }
    sort16_desc(c);
    merge_into16(L, c);
}

__global__ __launch_bounds__(256, 4) void k2_gram(const u16* __restrict__ xth,
                                                  const u16* __restrict__ xtl,
                                                  const float* __restrict__ sq,
                                                  u32* __restrict__ cand) {
    __shared__ char pool[8192];        // col-points tile (hi only, XOR-swizzled)
    int tid = threadIdx.x;
    int lane = tid & 63, w = tid >> 6;
    int l31 = lane & 31, lh = lane >> 5;
    int b = blockIdx.x & 7;
    int rt = (blockIdx.x >> 3) & 31;
    int ch = blockIdx.x >> 8;
    int r0 = rt * 128;
    int cb = ch * 1024;
    size_t bbase = (size_t)b * NPTS;

    // resident row-point fragments (second MFMA operand): lane l31 = row
    short8v Ah[4], Al[4];
    {
        const u16* pa = xth + (bbase + r0 + 32 * w + l31) * 64 + 8 * lh;
        const u16* pl = xtl + (bbase + r0 + 32 * w + l31) * 64 + 8 * lh;
#pragma unroll
        for (int s = 0; s < 4; s++) {
            Ah[s] = *(const short8v*)(pa + 16 * s);
            Al[s] = *(const short8v*)(pl + 16 * s);
        }
    }

    u32 L[16];
#pragma unroll
    for (int i = 0; i < 16; i++) L[i] = 0u;

    stage_tile(xth + (bbase + cb) * 64, pool, w, lane);
    __syncthreads();

    for (int t = 0; t < 16; t++) {
        int n1 = cb + t * 64;
        const float* sqp = sq + bbase + n1;

        float16v a0 = {};
#pragma unroll
        for (int s = 0; s < 4; s++) {
            int gx = 2 * s + lh;
            int sw = (gx ^ (l31 & 7)) << 4;
            short8v bh0 = *(const short8v*)(pool + l31 * 128 + sw);
            a0 = MFMA32(bh0, Ah[s], a0);    // D[m][n]: n(lane&31)=row, m(regs)=col
            a0 = MFMA32(bh0, Al[s], a0);
        }
        sel_half(a0, sqp, n1, lh, L);

        float16v a1 = {};
#pragma unroll
        for (int s = 0; s < 4; s++) {
            int gx = 2 * s + lh;
            int sw = (gx ^ (l31 & 7)) << 4;
            short8v bh1 = *(const short8v*)(pool + (32 + l31) * 128 + sw);
            a1 = MFMA32(bh1, Ah[s], a1);
            a1 = MFMA32(bh1, Al[s], a1);
        }
        __syncthreads();                // all waves done reading pool
        if (t < 15)
            stage_tile(xth + (bbase + n1 + 64) * 64, pool, w, lane);
        sel_half(a1, sqp + 32, n1 + 32, lh, L);    // hides load latency
        __syncthreads();                // drains vmcnt -> next tile ready
    }

    // merge the row's two class-lists (lh partner = lane^32, same row l31)
    u32 M[16];
#pragma unroll
    for (int i = 0; i < 16; i++) {
        u32 pv = __shfl_xor(L[15 - i], 32);
        M[i] = umaxu(L[i], pv);
    }
#pragma unroll
    for (int j = 8; j >= 1; j >>= 1)
#pragma unroll
        for (int i = 0; i < 16; i++)
            if ((i & j) == 0) {
                int p = i | j;
                u32 a = M[i], b2 = M[p];
                M[i] = umaxu(a, b2);
                M[p] = uminu(a, b2);
            }
    if (lane < 32) {
        u32* cr = cand + (bbase + r0 + 32 * w + l31) * 64 + ch * 16;
#pragma unroll
        for (int q = 0; q < 4; q++) {
            uint4 v;
            v.x = M[4 * q]; v.y = M[4 * q + 1]; v.z = M[4 * q + 2]; v.w = M[4 * q + 3];
            *(uint4*)(cr + 4 * q) = v;
        }
    }
}

// ---------------------------------------------------------------------------
// k1: y1 only; Wt1 staged from W. (validated r10-r11)
// ---------------------------------------------------------------------------
__global__ __launch_bounds__(256) void k1_prep(const float* __restrict__ x,
                                               const float* __restrict__ W,
                                               float* __restrict__ y1) {
    __shared__ float Xt[64][128];
    __shared__ float Wt[64][64];
    int tid = threadIdx.x;
    int gr0 = blockIdx.x * 128;
    int b = gr0 >> 12;
    int n0 = gr0 & 4095;
    const float* xb = x + (size_t)b * (CDIM * NPTS) + n0;

    for (int k = 0; k < 32; k++) {
        int f = tid + 256 * k;
        int c = f >> 7, j = f & 127;
        Xt[c][j] = xb[(size_t)c * NPTS + j];
    }
    for (int k = 0; k < 16; k++) {
        int f = tid + 256 * k;
        int c = f >> 6, o = f & 63;
        Wt[c][o] = W[o * 128 + c];
    }
    __syncthreads();

    int tr = tid & 15, tc = tid >> 4;
    float acc[8][4];
#pragma unroll
    for (int i = 0; i < 8; i++)
#pragma unroll
        for (int j = 0; j < 4; j++) acc[i][j] = 0.f;

#pragma unroll 4
    for (int c = 0; c < 64; c++) {
        float a[8], bb[4];
        *(float4*)&a[0] = *(const float4*)&Xt[c][8 * tr];
        *(float4*)&a[4] = *(const float4*)&Xt[c][8 * tr + 4];
        *(float4*)&bb[0] = *(const float4*)&Wt[c][4 * tc];
#pragma unroll
        for (int i = 0; i < 8; i++)
#pragma unroll
            for (int j = 0; j < 4; j++) acc[i][j] = fmaf(a[i], bb[j], acc[i][j]);
    }

#pragma unroll
    for (int i = 0; i < 8; i++) {
        int r = gr0 + 8 * tr + i;
        float4 s0;
        s0.x = acc[i][0]; s0.y = acc[i][1]; s0.z = acc[i][2]; s0.w = acc[i][3];
        *(float4*)(y1 + (size_t)r * 64 + 4 * tc) = s0;
    }
}

// ---------------------------------------------------------------------------
// k2b3: FUSED rescore + top-20 + output (validated r11). Final u64 selection
// now a 32-wide bitonic (keys only in lanes 0-31; 15 stages vs 21).
// ---------------------------------------------------------------------------
__global__ __launch_bounds__(256) void k2b3(const float* __restrict__ xtf,
                                            const float* __restrict__ sq,
                                            const u32* __restrict__ cand,
                                            const float* __restrict__ y1,
                                            const float* __restrict__ wt2g,
                                            const float* __restrict__ bias,
                                            float* __restrict__ out) {
    __shared__ float wt2[64][64];   // (W2-W1)^T : wt2[c][o]
    __shared__ float xr[4][64];
    __shared__ float dd[4][32];
    __shared__ u32 cols[4][32];
    __shared__ int ids[4][KSEL];
    __shared__ float outT[64][5];
    int tid = threadIdx.x;
    int lane = tid & 63, w = tid >> 6;
    int bid = blockIdx.x;
    int b = bid & 7;                       // batch == XCD slot
    int n0 = (bid >> 3) * 4;
    int n = n0 + w;
    size_t row = (size_t)b * NPTS + n;
    size_t bbase = (size_t)b * NPTS;

#pragma unroll
    for (int k = 0; k < 4; k++) {
        int f = tid + 256 * k;
        ((float4*)wt2)[f] = ((const float4*)wt2g)[f];
    }
    if (lane < 16)
        *(float4*)&xr[w][lane * 4] = *(const float4*)(xtf + row * 64 + lane * 4);
    u32 key = cand[row * 64 + lane];
    __syncthreads();

    // bitonic sort-64 desc on quantized keys (validated r8-r11)
#pragma unroll
    for (u32 k = 2; k <= 64; k <<= 1) {
#pragma unroll
        for (u32 j2 = k >> 1; j2 >= 1; j2 >>= 1) {
            bool up = ((lane & k) == 0);
            bool lower = ((lane & j2) == 0);
            u32 p = __shfl_xor(key, j2);
            u32 mx = (key > p) ? key : p, mn = (key > p) ? p : key;
            key = (lower == up) ? mx : mn;
        }
    }
    if (lane < 32) cols[w][lane] = key & 0xFFFu;

    // cooperative exact rescore: 2 passes x 16 candidates, 4 lanes each
    int s = lane & 3, g = lane >> 2;
    float4 xq[4];
#pragma unroll
    for (int q = 0; q < 4; q++) xq[q] = *(const float4*)&xr[w][16 * q + 4 * s];

#pragma unroll
    for (int p = 0; p < 2; p++) {
        int m = cols[w][p * 16 + g];
        const float* pm = xtf + (bbase + m) * 64;
        float d = 0.f;
#pragma unroll
        for (int q = 0; q < 4; q++) {
            float4 v = *(const float4*)(pm + 16 * q + 4 * s);
            d = fmaf(v.x, xq[q].x, d); d = fmaf(v.y, xq[q].y, d);
            d = fmaf(v.z, xq[q].z, d); d = fmaf(v.w, xq[q].w, d);
        }
        d += __shfl_xor(d, 1);
        d += __shfl_xor(d, 2);
        if (s == 0) dd[w][p * 16 + g] = d;
    }

    // exact u64 keys + top-20: 32-wide bitonic (lanes >=32 idle sentinels)
    u64 kE = 0;
    if (lane < 32) {
        int m = (int)cols[w][lane];
        float sE = fmaf(2.f, dd[w][lane], -sq[bbase + m]);
        kE = ((u64)ordf(sE) << 32) | (u32)(~(u32)m);
    }
#pragma unroll
    for (u32 k = 2; k <= 32; k <<= 1) {
#pragma unroll
        for (u32 j2 = k >> 1; j2 >= 1; j2 >>= 1) {
            bool up = ((lane & k) == 0);
            bool lower = ((lane & j2) == 0);
            u64 p = __shfl_xor(kE, j2);
            u64 mx = (kE > p) ? kE : p, mn = (kE > p) ? p : kE;
            kE = (lower == up) ? mx : mn;
        }
    }
    if (lane < KSEL) ids[w][lane] = (int)(~(u32)kE);

    const float* y1b = y1 + bbase * 64;
    float acc = -FLT_MAX;
#pragma unroll
    for (int k = 0; k < KSEL; k++) {
        int m = ids[w][k];
        acc = fmaxf(acc, y1b[(size_t)m * 64 + lane]);
    }
    float acc2 = 0.f;
#pragma unroll 8
    for (int c = 0; c < 64; c++)
        acc2 = fmaf(xr[w][c], wt2[c][lane], acc2);
    outT[lane][w] = acc + acc2 + bias[lane];
    __syncthreads();

    if (tid < 64) {
        float4 v;
        v.x = outT[tid][0]; v.y = outT[tid][1];
        v.z = outT[tid][2]; v.w = outT[tid][3];
        *(float4*)(out + ((size_t)(b * 64 + tid)) * NPTS + n0) = v;
    }
}

// ---------------------------------------------------------------------------
extern "C" void kernel_launch(void* const* d_in, const int* in_sizes, int n_in,
                              void* d_out, int out_size, void* d_ws, size_t ws_size,
                              hipStream_t stream) {
    const float* x    = (const float*)d_in[0];   // (8, 64, 4096)
    const float* W    = (const float*)d_in[1];   // (64, 128)
    const float* bias = (const float*)d_in[2];   // (64,)
    float* out = (float*)d_out;                  // (8, 64, 4096)
    float* ws = (float*)d_ws;

    u16* xth   = (u16*)ws;                  // [0,4MB)   dies after k2
    u16* xtl   = (u16*)(ws + F_XTL);        // [4,8MB)   dies after k2
    u32* candb = (u32*)(ws + F_CAND);       // [8,16MB)
    float* xtf = ws + F_XTF;                // [16,24MB)
    float* sq  = ws + F_SQ;                 // [24MB, +128KB)
    float* wt2g = ws + F_WT2;               // [+128KB, +16KB)
    float* y1  = ws;                        // overlays xth/xtl after k2

    hipLaunchKernelGGL(k0_wt2,  dim3(16),   dim3(256), 0, stream, W, wt2g);
    hipLaunchKernelGGL(p1_prep, dim3(512),  dim3(256), 0, stream, x, xtf, xth, xtl, sq);
    hipLaunchKernelGGL(k2_gram, dim3(1024), dim3(256), 0, stream, xth, xtl, sq, candb);
    hipLaunchKernelGGL(k1_prep, dim3(256),  dim3(256), 0, stream, x, W, y1);
    hipLaunchKernelGGL(k2b3,    dim3(8192), dim3(256), 0, stream, xtf, sq, candb, y1, wt2g, bias, out);
}

// Round 13
// 142.307 us; speedup vs baseline: 1.7437x; 1.0610x over previous
//
#include <hip/hip_runtime.h>
#include <float.h>

typedef unsigned long long u64;
typedef unsigned int u32;
typedef unsigned short u16;

#define NPTS 4096
#define CDIM 64
#define BATCH 8
#define KSEL 20

// ws layout in float-slots (total ~25.4 MB; r9 proved ws >= 26.6 MB):
//   [0,8MB) xth/xtl (scaled bf16 split; y1 overlays after k2)
//   [8,16MB) cand   [16,24MB) xtf   then sq(128K), wt2g(16K), sqb(128K)
#define F_XTL (BATCH * NPTS * 32)               // 1M floats
#define F_CAND (2 * BATCH * NPTS * 32)          // 2M
#define F_XTF (4 * BATCH * NPTS * 32)           // 4M
#define F_SQ (6 * BATCH * NPTS * 32)            // 6M
#define F_WT2 (F_SQ + BATCH * NPTS)             // +32K floats
#define F_SQB (F_WT2 + 64 * 64)                 // +4K floats

typedef __attribute__((ext_vector_type(8))) short short8v;   // 8 bf16 (4 VGPR)
typedef __attribute__((ext_vector_type(16))) float float16v; // MFMA 32x32 acc

#define MFMA32(a, b, c) __builtin_amdgcn_mfma_f32_32x32x16_bf16(a, b, c, 0, 0, 0)

__device__ __forceinline__ u32 ordf(float f) {
    u32 u = __float_as_uint(f);
    return (u >> 31) ? ~u : (u | 0x80000000u);
}
__device__ __forceinline__ u32 umaxu(u32 a, u32 b) { return a > b ? a : b; }
__device__ __forceinline__ u32 uminu(u32 a, u32 b) { return a < b ? a : b; }

__device__ __forceinline__ void load_lds_16(const void* g, void* l) {
    __builtin_amdgcn_global_load_lds(
        (const __attribute__((address_space(1))) unsigned int*)g,
        (__attribute__((address_space(3))) unsigned int*)l, 16, 0, 0);
}

#define CE(i, j) { u32 a_ = c[i], b_ = c[j]; c[i] = umaxu(a_, b_); c[j] = uminu(a_, b_); }

// Batcher odd-even merge sort, 16 u32 keys, descending. 63 CEs. (validated r7-r12)
__device__ __forceinline__ void sort16_desc(u32 (&c)[16]) {
    CE(0,1) CE(2,3) CE(4,5) CE(6,7) CE(8,9) CE(10,11) CE(12,13) CE(14,15)
    CE(0,2) CE(1,3) CE(4,6) CE(5,7) CE(8,10) CE(9,11) CE(12,14) CE(13,15)
    CE(1,2) CE(5,6) CE(9,10) CE(13,14)
    CE(0,4) CE(1,5) CE(2,6) CE(3,7) CE(8,12) CE(9,13) CE(10,14) CE(11,15)
    CE(2,4) CE(3,5) CE(10,12) CE(11,13)
    CE(1,2) CE(3,4) CE(5,6) CE(9,10) CE(11,12) CE(13,14)
    CE(0,8) CE(1,9) CE(2,10) CE(3,11) CE(4,12) CE(5,13) CE(6,14) CE(7,15)
    CE(4,8) CE(5,9) CE(6,10) CE(7,11)
    CE(2,4) CE(3,5) CE(6,8) CE(7,9) CE(10,12) CE(11,13)
    CE(1,2) CE(3,4) CE(5,6) CE(7,8) CE(9,10) CE(11,12) CE(13,14)
}
#undef CE

// L (desc,16) <- top-16 of L ∪ c (desc,16): max-half + bitonic merge
__device__ __forceinline__ void merge_into16(u32 (&L)[16], const u32 (&c)[16]) {
#pragma unroll
    for (int i = 0; i < 16; i++) L[i] = umaxu(L[i], c[15 - i]);
#pragma unroll
    for (int j = 8; j >= 1; j >>= 1)
#pragma unroll
        for (int i = 0; i < 16; i++)
            if ((i & j) == 0) {
                int p = i | j;
                u32 a = L[i], b = L[p];
                L[i] = umaxu(a, b);
                L[p] = uminu(a, b);
            }
}

// ---------------------------------------------------------------------------
// p1 (+k0 folded): blocks <512: transpose x -> xtf (raw fp32), xth/xtl
// (bf16 hi/lo split of sqrt(2)*x, RNE), sq, sqb=1024-sq.
// blocks >=512: wt2g[c*64+o] = W[o*128+64+c] - W[o*128+c].
// ---------------------------------------------------------------------------
__global__ __launch_bounds__(256) void p1_prep(const float* __restrict__ x,
                                               const float* __restrict__ W,
                                               float* __restrict__ xtf,
                                               u16* __restrict__ xth,
                                               u16* __restrict__ xtl,
                                               float* __restrict__ sq,
                                               float* __restrict__ sqb,
                                               float* __restrict__ wt2g) {
    __shared__ float Xp[64][65];
    int tid = threadIdx.x;
    if (blockIdx.x >= 512) {                    // k0 branch (16 blocks)
        int f = (blockIdx.x - 512) * 256 + tid;
        if (f < 64 * 64) {
            int c = f >> 6, o = f & 63;
            wt2g[f] = W[o * 128 + 64 + c] - W[o * 128 + c];
        }
        return;
    }
    int b = blockIdx.x >> 6;
    int n0 = (blockIdx.x & 63) * 64;
    const float* xb = x + (size_t)b * (CDIM * NPTS);
    int j = tid & 63, cq = tid >> 6;
#pragma unroll
    for (int i = 0; i < 16; i++) {
        int c = cq * 16 + i;
        Xp[c][j] = xb[(size_t)c * NPTS + n0 + j];
    }
    __syncthreads();
    if (tid < 64) {
        float s = 0.f;
        for (int c = 0; c < 64; c++) { float v = Xp[c][tid]; s = fmaf(v, v, s); }
        sq[(size_t)b * NPTS + n0 + tid] = s;
        sqb[(size_t)b * NPTS + n0 + tid] = 1024.f - s;
    }
    int n = tid >> 2, c0 = (tid & 3) * 16;
    float vv[16];
#pragma unroll
    for (int i = 0; i < 16; i++) vv[i] = Xp[c0 + i][n];
    size_t rowb = ((size_t)b * NPTS + n0 + n) * 64 + c0;
#pragma unroll
    for (int q = 0; q < 4; q++) {
        float4 f;
        f.x = vv[4 * q]; f.y = vv[4 * q + 1]; f.z = vv[4 * q + 2]; f.w = vv[4 * q + 3];
        *(float4*)(xtf + rowb + 4 * q) = f;
    }
    u16 hb[16], lb[16];
#pragma unroll
    for (int i = 0; i < 16; i++) {
        float v = vv[i] * 1.41421356237f;       // sqrt(2) pre-scale: MFMA = 2*dot
        u32 bv = __float_as_uint(v);
        u32 h = (bv + 0x7FFFu + ((bv >> 16) & 1u)) >> 16;    // RNE bf16
        float hf = __uint_as_float(h << 16);
        float lf = v - hf;
        u32 bl = __float_as_uint(lf);
        u32 lo = (bl + 0x7FFFu + ((bl >> 16) & 1u)) >> 16;
        hb[i] = (u16)h; lb[i] = (u16)lo;
    }
    uint4 H0, H1, L0, L1;
    H0.x = hb[0] | ((u32)hb[1] << 16);  H0.y = hb[2] | ((u32)hb[3] << 16);
    H0.z = hb[4] | ((u32)hb[5] << 16);  H0.w = hb[6] | ((u32)hb[7] << 16);
    H1.x = hb[8] | ((u32)hb[9] << 16);  H1.y = hb[10] | ((u32)hb[11] << 16);
    H1.z = hb[12] | ((u32)hb[13] << 16); H1.w = hb[14] | ((u32)hb[15] << 16);
    L0.x = lb[0] | ((u32)lb[1] << 16);  L0.y = lb[2] | ((u32)lb[3] << 16);
    L0.z = lb[4] | ((u32)lb[5] << 16);  L0.w = lb[6] | ((u32)lb[7] << 16);
    L1.x = lb[8] | ((u32)lb[9] << 16);  L1.y = lb[10] | ((u32)lb[11] << 16);
    L1.z = lb[12] | ((u32)lb[13] << 16); L1.w = lb[14] | ((u32)lb[15] << 16);
    *(uint4*)(xth + rowb) = H0;
    *(uint4*)(xth + rowb + 8) = H1;
    *(uint4*)(xtl + rowb) = L0;
    *(uint4*)(xtl + rowb + 8) = L1;
}

// ---------------------------------------------------------------------------
// k2: swapped-operand MFMA Gram with BIAS-IN-ACCUMULATOR: acc initialized
// from sqb (4 aligned float4 per half) so post-MFMA A[r] = score+1024
// directly (inputs sqrt(2)-scaled -> MFMA yields 2*dot). Key build = one
// and_or per candidate. Per-lane top-16; class merge -> chunk-top-16 keys.
// ---------------------------------------------------------------------------
__device__ __forceinline__ void stage_tile(const u16* __restrict__ srcb,
                                           char* lds, int w, int lane) {
#pragma unroll
    for (int i = 0; i < 2; i++) {
        int G = w * 128 + i * 64 + lane;
        int rr = G >> 3, gp = G & 7;
        const u16* src = srcb + rr * 64 + ((gp ^ (rr & 7)) << 3);
        char* dst = lds + (w * 128 + i * 64) * 16;
        load_lds_16(src, dst);
    }
}

// keys straight from biased acc regs: col(r) = colbase2 + 8*(r>>2) + (r&3)
__device__ __forceinline__ void sel_half(const float16v& A, int colbase2,
                                         u32 (&L)[16]) {
    u32 c[16];
#pragma unroll
    for (int q = 0; q < 4; q++) {
        u32 cg = (u32)(colbase2 + 8 * q);
        c[4 * q + 0] = (__float_as_uint(A[4 * q + 0]) & 0xFFFFF000u) | (cg + 0);
        c[4 * q + 1] = (__float_as_uint(A[4 * q + 1]) & 0xFFFFF000u) | (cg + 1);
        c[4 * q + 2] = (__float_as_uint(A[4 * q + 2]) & 0xFFFFF000u) | (cg + 2);
        c[4 * q + 3] = (__float_as_uint(A[4 * q + 3]) & 0xFFFFF000u) | (cg + 3);
    }
    sort16_desc(c);
    merge_into16(L, c);
}

__global__ __launch_bounds__(256, 4) void k2_gram(const u16* __restrict__ xth,
                                                  const u16* __restrict__ xtl,
                                                  const float* __restrict__ sqb,
                                                  u32* __restrict__ cand) {
    __shared__ char pool[8192];        // col-points tile (hi only, XOR-swizzled)
    int tid = threadIdx.x;
    int lane = tid & 63, w = tid >> 6;
    int l31 = lane & 31, lh = lane >> 5;
    int b = blockIdx.x & 7;
    int rt = (blockIdx.x >> 3) & 31;
    int ch = blockIdx.x >> 8;
    int r0 = rt * 128;
    int cb = ch * 1024;
    size_t bbase = (size_t)b * NPTS;

    // resident row-point fragments (second MFMA operand): lane l31 = row
    short8v Ah[4], Al[4];
    {
        const u16* pa = xth + (bbase + r0 + 32 * w + l31) * 64 + 8 * lh;
        const u16* pl = xtl + (bbase + r0 + 32 * w + l31) * 64 + 8 * lh;
#pragma unroll
        for (int s = 0; s < 4; s++) {
            Ah[s] = *(const short8v*)(pa + 16 * s);
            Al[s] = *(const short8v*)(pl + 16 * s);
        }
    }

    u32 L[16];
#pragma unroll
    for (int i = 0; i < 16; i++) L[i] = 0u;

    stage_tile(xth + (bbase + cb) * 64, pool, w, lane);
    __syncthreads();

    for (int t = 0; t < 16; t++) {
        int n1 = cb + t * 64;
        const float* sqbp = sqb + bbase + n1 + 4 * lh;

        // acc init = bias row (score offset); loads land in acc quarters
        float16v a0, a1;
#pragma unroll
        for (int q = 0; q < 4; q++) {
            ((float4*)&a0)[q] = *(const float4*)(sqbp + 8 * q);
            ((float4*)&a1)[q] = *(const float4*)(sqbp + 32 + 8 * q);
        }

#pragma unroll
        for (int s = 0; s < 4; s++) {
            int gx = 2 * s + lh;
            int sw = (gx ^ (l31 & 7)) << 4;
            short8v bh0 = *(const short8v*)(pool + l31 * 128 + sw);
            a0 = MFMA32(bh0, Ah[s], a0);    // n(lane&31)=row, m(regs)=col
            a0 = MFMA32(bh0, Al[s], a0);
        }
        sel_half(a0, n1 + 4 * lh, L);

#pragma unroll
        for (int s = 0; s < 4; s++) {
            int gx = 2 * s + lh;
            int sw = (gx ^ (l31 & 7)) << 4;
            short8v bh1 = *(const short8v*)(pool + (32 + l31) * 128 + sw);
            a1 = MFMA32(bh1, Ah[s], a1);
            a1 = MFMA32(bh1, Al[s], a1);
        }
        __syncthreads();                // all waves done reading pool
        if (t < 15)
            stage_tile(xth + (bbase + n1 + 64) * 64, pool, w, lane);
        sel_half(a1, n1 + 32 + 4 * lh, L);    // hides load latency
        __syncthreads();                // drains vmcnt -> next tile ready
    }

    // merge the row's two class-lists (partner lane = lane^32, same row l31)
    u32 M[16];
#pragma unroll
    for (int i = 0; i < 16; i++) {
        u32 pv = __shfl_xor(L[15 - i], 32);
        M[i] = umaxu(L[i], pv);
    }
#pragma unroll
    for (int j = 8; j >= 1; j >>= 1)
#pragma unroll
        for (int i = 0; i < 16; i++)
            if ((i & j) == 0) {
                int p = i | j;
                u32 a = M[i], b2 = M[p];
                M[i] = umaxu(a, b2);
                M[p] = uminu(a, b2);
            }
    if (lane < 32) {
        u32* cr = cand + (bbase + r0 + 32 * w + l31) * 64 + ch * 16;
#pragma unroll
        for (int q = 0; q < 4; q++) {
            uint4 v;
            v.x = M[4 * q]; v.y = M[4 * q + 1]; v.z = M[4 * q + 2]; v.w = M[4 * q + 3];
            *(uint4*)(cr + 4 * q) = v;
        }
    }
}

// ---------------------------------------------------------------------------
// k1: y1 only; Wt1 staged from W. (validated r10-r12)
// ---------------------------------------------------------------------------
__global__ __launch_bounds__(256) void k1_prep(const float* __restrict__ x,
                                               const float* __restrict__ W,
                                               float* __restrict__ y1) {
    __shared__ float Xt[64][128];
    __shared__ float Wt[64][64];
    int tid = threadIdx.x;
    int gr0 = blockIdx.x * 128;
    int b = gr0 >> 12;
    int n0 = gr0 & 4095;
    const float* xb = x + (size_t)b * (CDIM * NPTS) + n0;

    for (int k = 0; k < 32; k++) {
        int f = tid + 256 * k;
        int c = f >> 7, j = f & 127;
        Xt[c][j] = xb[(size_t)c * NPTS + j];
    }
    for (int k = 0; k < 16; k++) {
        int f = tid + 256 * k;
        int c = f >> 6, o = f & 63;
        Wt[c][o] = W[o * 128 + c];
    }
    __syncthreads();

    int tr = tid & 15, tc = tid >> 4;
    float acc[8][4];
#pragma unroll
    for (int i = 0; i < 8; i++)
#pragma unroll
        for (int j = 0; j < 4; j++) acc[i][j] = 0.f;

#pragma unroll 4
    for (int c = 0; c < 64; c++) {
        float a[8], bb[4];
        *(float4*)&a[0] = *(const float4*)&Xt[c][8 * tr];
        *(float4*)&a[4] = *(const float4*)&Xt[c][8 * tr + 4];
        *(float4*)&bb[0] = *(const float4*)&Wt[c][4 * tc];
#pragma unroll
        for (int i = 0; i < 8; i++)
#pragma unroll
            for (int j = 0; j < 4; j++) acc[i][j] = fmaf(a[i], bb[j], acc[i][j]);
    }

#pragma unroll
    for (int i = 0; i < 8; i++) {
        int r = gr0 + 8 * tr + i;
        float4 s0;
        s0.x = acc[i][0]; s0.y = acc[i][1]; s0.z = acc[i][2]; s0.w = acc[i][3];
        *(float4*)(y1 + (size_t)r * 64 + 4 * tc) = s0;
    }
}

// ---------------------------------------------------------------------------
// k2b3: FUSED rescore + top-20 + output. (validated r11-r12)
// ---------------------------------------------------------------------------
__global__ __launch_bounds__(256) void k2b3(const float* __restrict__ xtf,
                                            const float* __restrict__ sq,
                                            const u32* __restrict__ cand,
                                            const float* __restrict__ y1,
                                            const float* __restrict__ wt2g,
                                            const float* __restrict__ bias,
                                            float* __restrict__ out) {
    __shared__ float wt2[64][64];   // (W2-W1)^T : wt2[c][o]
    __shared__ float xr[4][64];
    __shared__ float dd[4][32];
    __shared__ u32 cols[4][32];
    __shared__ int ids[4][KSEL];
    __shared__ float outT[64][5];
    int tid = threadIdx.x;
    int lane = tid & 63, w = tid >> 6;
    int bid = blockIdx.x;
    int b = bid & 7;                       // batch == XCD slot
    int n0 = (bid >> 3) * 4;
    int n = n0 + w;
    size_t row = (size_t)b * NPTS + n;
    size_t bbase = (size_t)b * NPTS;

#pragma unroll
    for (int k = 0; k < 4; k++) {
        int f = tid + 256 * k;
        ((float4*)wt2)[f] = ((const float4*)wt2g)[f];
    }
    if (lane < 16)
        *(float4*)&xr[w][lane * 4] = *(const float4*)(xtf + row * 64 + lane * 4);
    u32 key = cand[row * 64 + lane];
    __syncthreads();

    // bitonic sort-64 desc on quantized keys (validated r8-r12)
#pragma unroll
    for (u32 k = 2; k <= 64; k <<= 1) {
#pragma unroll
        for (u32 j2 = k >> 1; j2 >= 1; j2 >>= 1) {
            bool up = ((lane & k) == 0);
            bool lower = ((lane & j2) == 0);
            u32 p = __shfl_xor(key, j2);
            u32 mx = (key > p) ? key : p, mn = (key > p) ? p : key;
            key = (lower == up) ? mx : mn;
        }
    }
    if (lane < 32) cols[w][lane] = key & 0xFFFu;

    // cooperative exact rescore: 2 passes x 16 candidates, 4 lanes each
    int s = lane & 3, g = lane >> 2;
    float4 xq[4];
#pragma unroll
    for (int q = 0; q < 4; q++) xq[q] = *(const float4*)&xr[w][16 * q + 4 * s];

#pragma unroll
    for (int p = 0; p < 2; p++) {
        int m = cols[w][p * 16 + g];
        const float* pm = xtf + (bbase + m) * 64;
        float d = 0.f;
#pragma unroll
        for (int q = 0; q < 4; q++) {
            float4 v = *(const float4*)(pm + 16 * q + 4 * s);
            d = fmaf(v.x, xq[q].x, d); d = fmaf(v.y, xq[q].y, d);
            d = fmaf(v.z, xq[q].z, d); d = fmaf(v.w, xq[q].w, d);
        }
        d += __shfl_xor(d, 1);
        d += __shfl_xor(d, 2);
        if (s == 0) dd[w][p * 16 + g] = d;
    }

    // exact u64 keys + top-20: 32-wide bitonic (lanes >=32 sentinels)
    u64 kE = 0;
    if (lane < 32) {
        int m = (int)cols[w][lane];
        float sE = fmaf(2.f, dd[w][lane], -sq[bbase + m]);
        kE = ((u64)ordf(sE) << 32) | (u32)(~(u32)m);
    }
#pragma unroll
    for (u32 k = 2; k <= 32; k <<= 1) {
#pragma unroll
        for (u32 j2 = k >> 1; j2 >= 1; j2 >>= 1) {
            bool up = ((lane & k) == 0);
            bool lower = ((lane & j2) == 0);
            u64 p = __shfl_xor(kE, j2);
            u64 mx = (kE > p) ? kE : p, mn = (kE > p) ? p : kE;
            kE = (lower == up) ? mx : mn;
        }
    }
    if (lane < KSEL) ids[w][lane] = (int)(~(u32)kE);

    const float* y1b = y1 + bbase * 64;
    float acc = -FLT_MAX;
#pragma unroll
    for (int k = 0; k < KSEL; k++) {
        int m = ids[w][k];
        acc = fmaxf(acc, y1b[(size_t)m * 64 + lane]);
    }
    float acc2 = 0.f;
#pragma unroll 8
    for (int c = 0; c < 64; c++)
        acc2 = fmaf(xr[w][c], wt2[c][lane], acc2);
    outT[lane][w] = acc + acc2 + bias[lane];
    __syncthreads();

    if (tid < 64) {
        float4 v;
        v.x = outT[tid][0]; v.y = outT[tid][1];
        v.z = outT[tid][2]; v.w = outT[tid][3];
        *(float4*)(out + ((size_t)(b * 64 + tid)) * NPTS + n0) = v;
    }
}

// ---------------------------------------------------------------------------
extern "C" void kernel_launch(void* const* d_in, const int* in_sizes, int n_in,
                              void* d_out, int out_size, void* d_ws, size_t ws_size,
                              hipStream_t stream) {
    const float* x    = (const float*)d_in[0];   // (8, 64, 4096)
    const float* W    = (const float*)d_in[1];   // (64, 128)
    const float* bias = (const float*)d_in[2];   // (64,)
    float* out = (float*)d_out;                  // (8, 64, 4096)
    float* ws = (float*)d_ws;

    u16* xth    = (u16*)ws;                 // [0,4MB)   dies after k2
    u16* xtl    = (u16*)(ws + F_XTL);       // [4,8MB)   dies after k2
    u32* candb  = (u32*)(ws + F_CAND);      // [8,16MB)
    float* xtf  = ws + F_XTF;               // [16,24MB)
    float* sq   = ws + F_SQ;                // 128 KB
    float* wt2g = ws + F_WT2;               // 16 KB
    float* sqb  = ws + F_SQB;               // 128 KB
    float* y1   = ws;                       // overlays xth/xtl after k2

    hipLaunchKernelGGL(p1_prep, dim3(528),  dim3(256), 0, stream,
                       x, W, xtf, xth, xtl, sq, sqb, wt2g);
    hipLaunchKernelGGL(k2_gram, dim3(1024), dim3(256), 0, stream, xth, xtl, sqb, candb);
    hipLaunchKernelGGL(k1_prep, dim3(256),  dim3(256), 0, stream, x, W, y1);
    hipLaunchKernelGGL(k2b3,    dim3(8192), dim3(256), 0, stream,
                       xtf, sq, candb, y1, wt2g, bias, out);
}

// Round 14
// 141.695 us; speedup vs baseline: 1.7512x; 1.0043x over previous
//
#include <hip/hip_runtime.h>
#include <float.h>

typedef unsigned long long u64;
typedef unsigned int u32;
typedef unsigned short u16;

#define NPTS 4096
#define CDIM 64
#define BATCH 8
#define KSEL 20

// ws layout in float-slots (total ~25.4 MB; r9 proved ws >= 26.6 MB):
#define F_XTL (BATCH * NPTS * 32)               // 1M floats
#define F_CAND (2 * BATCH * NPTS * 32)          // 2M
#define F_XTF (4 * BATCH * NPTS * 32)           // 4M
#define F_SQ (6 * BATCH * NPTS * 32)            // 6M
#define F_WT2 (F_SQ + BATCH * NPTS)             // +32K floats
#define F_SQB (F_WT2 + 64 * 64)                 // +4K floats

typedef __attribute__((ext_vector_type(8))) short short8v;   // 8 bf16 (4 VGPR)
typedef __attribute__((ext_vector_type(16))) float float16v; // MFMA 32x32 acc

#define MFMA32(a, b, c) __builtin_amdgcn_mfma_f32_32x32x16_bf16(a, b, c, 0, 0, 0)

__device__ __forceinline__ u32 ordf(float f) {
    u32 u = __float_as_uint(f);
    return (u >> 31) ? ~u : (u | 0x80000000u);
}
__device__ __forceinline__ u32 umaxu(u32 a, u32 b) { return a > b ? a : b; }
__device__ __forceinline__ u32 uminu(u32 a, u32 b) { return a < b ? a : b; }

__device__ __forceinline__ void load_lds_16(const void* g, void* l) {
    __builtin_amdgcn_global_load_lds(
        (const __attribute__((address_space(1))) unsigned int*)g,
        (__attribute__((address_space(3))) unsigned int*)l, 16, 0, 0);
}

#define CE(i, j) { u32 a_ = c[i], b_ = c[j]; c[i] = umaxu(a_, b_); c[j] = uminu(a_, b_); }

// Batcher odd-even merge sort, 16 u32 keys, descending. 63 CEs. (validated r7-r13)
__device__ __forceinline__ void sort16_desc(u32 (&c)[16]) {
    CE(0,1) CE(2,3) CE(4,5) CE(6,7) CE(8,9) CE(10,11) CE(12,13) CE(14,15)
    CE(0,2) CE(1,3) CE(4,6) CE(5,7) CE(8,10) CE(9,11) CE(12,14) CE(13,15)
    CE(1,2) CE(5,6) CE(9,10) CE(13,14)
    CE(0,4) CE(1,5) CE(2,6) CE(3,7) CE(8,12) CE(9,13) CE(10,14) CE(11,15)
    CE(2,4) CE(3,5) CE(10,12) CE(11,13)
    CE(1,2) CE(3,4) CE(5,6) CE(9,10) CE(11,12) CE(13,14)
    CE(0,8) CE(1,9) CE(2,10) CE(3,11) CE(4,12) CE(5,13) CE(6,14) CE(7,15)
    CE(4,8) CE(5,9) CE(6,10) CE(7,11)
    CE(2,4) CE(3,5) CE(6,8) CE(7,9) CE(10,12) CE(11,13)
    CE(1,2) CE(3,4) CE(5,6) CE(7,8) CE(9,10) CE(11,12) CE(13,14)
}
#undef CE

// L (desc,16) <- top-16 of L ∪ c (desc,16): max-half + bitonic merge
__device__ __forceinline__ void merge_into16(u32 (&L)[16], const u32 (&c)[16]) {
#pragma unroll
    for (int i = 0; i < 16; i++) L[i] = umaxu(L[i], c[15 - i]);
#pragma unroll
    for (int j = 8; j >= 1; j >>= 1)
#pragma unroll
        for (int i = 0; i < 16; i++)
            if ((i & j) == 0) {
                int p = i | j;
                u32 a = L[i], b = L[p];
                L[i] = umaxu(a, b);
                L[p] = uminu(a, b);
            }
}

// ---------------------------------------------------------------------------
// p1 (+k0 folded): blocks <512: transpose x -> xtf, xth/xtl (bf16 split of
// sqrt(2)x), sq, sqb=1024-sq. blocks >=512: wt2g. (validated r13)
// ---------------------------------------------------------------------------
__global__ __launch_bounds__(256) void p1_prep(const float* __restrict__ x,
                                               const float* __restrict__ W,
                                               float* __restrict__ xtf,
                                               u16* __restrict__ xth,
                                               u16* __restrict__ xtl,
                                               float* __restrict__ sq,
                                               float* __restrict__ sqb,
                                               float* __restrict__ wt2g) {
    __shared__ float Xp[64][65];
    int tid = threadIdx.x;
    if (blockIdx.x >= 512) {                    // k0 branch (16 blocks)
        int f = (blockIdx.x - 512) * 256 + tid;
        if (f < 64 * 64) {
            int c = f >> 6, o = f & 63;
            wt2g[f] = W[o * 128 + 64 + c] - W[o * 128 + c];
        }
        return;
    }
    int b = blockIdx.x >> 6;
    int n0 = (blockIdx.x & 63) * 64;
    const float* xb = x + (size_t)b * (CDIM * NPTS);
    int j = tid & 63, cq = tid >> 6;
#pragma unroll
    for (int i = 0; i < 16; i++) {
        int c = cq * 16 + i;
        Xp[c][j] = xb[(size_t)c * NPTS + n0 + j];
    }
    __syncthreads();
    if (tid < 64) {
        float s = 0.f;
        for (int c = 0; c < 64; c++) { float v = Xp[c][tid]; s = fmaf(v, v, s); }
        sq[(size_t)b * NPTS + n0 + tid] = s;
        sqb[(size_t)b * NPTS + n0 + tid] = 1024.f - s;
    }
    int n = tid >> 2, c0 = (tid & 3) * 16;
    float vv[16];
#pragma unroll
    for (int i = 0; i < 16; i++) vv[i] = Xp[c0 + i][n];
    size_t rowb = ((size_t)b * NPTS + n0 + n) * 64 + c0;
#pragma unroll
    for (int q = 0; q < 4; q++) {
        float4 f;
        f.x = vv[4 * q]; f.y = vv[4 * q + 1]; f.z = vv[4 * q + 2]; f.w = vv[4 * q + 3];
        *(float4*)(xtf + rowb + 4 * q) = f;
    }
    u16 hb[16], lb[16];
#pragma unroll
    for (int i = 0; i < 16; i++) {
        float v = vv[i] * 1.41421356237f;       // sqrt(2) pre-scale: MFMA = 2*dot
        u32 bv = __float_as_uint(v);
        u32 h = (bv + 0x7FFFu + ((bv >> 16) & 1u)) >> 16;    // RNE bf16
        float hf = __uint_as_float(h << 16);
        float lf = v - hf;
        u32 bl = __float_as_uint(lf);
        u32 lo = (bl + 0x7FFFu + ((bl >> 16) & 1u)) >> 16;
        hb[i] = (u16)h; lb[i] = (u16)lo;
    }
    uint4 H0, H1, L0, L1;
    H0.x = hb[0] | ((u32)hb[1] << 16);  H0.y = hb[2] | ((u32)hb[3] << 16);
    H0.z = hb[4] | ((u32)hb[5] << 16);  H0.w = hb[6] | ((u32)hb[7] << 16);
    H1.x = hb[8] | ((u32)hb[9] << 16);  H1.y = hb[10] | ((u32)hb[11] << 16);
    H1.z = hb[12] | ((u32)hb[13] << 16); H1.w = hb[14] | ((u32)hb[15] << 16);
    L0.x = lb[0] | ((u32)lb[1] << 16);  L0.y = lb[2] | ((u32)lb[3] << 16);
    L0.z = lb[4] | ((u32)lb[5] << 16);  L0.w = lb[6] | ((u32)lb[7] << 16);
    L1.x = lb[8] | ((u32)lb[9] << 16);  L1.y = lb[10] | ((u32)lb[11] << 16);
    L1.z = lb[12] | ((u32)lb[13] << 16); L1.w = lb[14] | ((u32)lb[15] << 16);
    *(uint4*)(xth + rowb) = H0;
    *(uint4*)(xth + rowb + 8) = H1;
    *(uint4*)(xtl + rowb) = L0;
    *(uint4*)(xtl + rowb + 8) = L1;
}

// ---------------------------------------------------------------------------
// k2: swapped-operand MFMA Gram, bias-in-accumulator (r13-validated), now
// DOUBLE-BUFFERED pool -> ONE barrier per tile (stage t+1 issued at tile-t
// start; barrier's implicit vmcnt(0) drain readies it).
// ---------------------------------------------------------------------------
__device__ __forceinline__ void stage_tile(const u16* __restrict__ srcb,
                                           char* lds, int w, int lane) {
#pragma unroll
    for (int i = 0; i < 2; i++) {
        int G = w * 128 + i * 64 + lane;
        int rr = G >> 3, gp = G & 7;
        const u16* src = srcb + rr * 64 + ((gp ^ (rr & 7)) << 3);
        char* dst = lds + (w * 128 + i * 64) * 16;
        load_lds_16(src, dst);
    }
}

// keys straight from biased acc regs: col(r) = colbase2 + 8*(r>>2) + (r&3)
__device__ __forceinline__ void sel_half(const float16v& A, int colbase2,
                                         u32 (&L)[16]) {
    u32 c[16];
#pragma unroll
    for (int q = 0; q < 4; q++) {
        u32 cg = (u32)(colbase2 + 8 * q);
        c[4 * q + 0] = (__float_as_uint(A[4 * q + 0]) & 0xFFFFF000u) | (cg + 0);
        c[4 * q + 1] = (__float_as_uint(A[4 * q + 1]) & 0xFFFFF000u) | (cg + 1);
        c[4 * q + 2] = (__float_as_uint(A[4 * q + 2]) & 0xFFFFF000u) | (cg + 2);
        c[4 * q + 3] = (__float_as_uint(A[4 * q + 3]) & 0xFFFFF000u) | (cg + 3);
    }
    sort16_desc(c);
    merge_into16(L, c);
}

__global__ __launch_bounds__(256, 4) void k2_gram(const u16* __restrict__ xth,
                                                  const u16* __restrict__ xtl,
                                                  const float* __restrict__ sqb,
                                                  u32* __restrict__ cand) {
    __shared__ char pool[2][8192];     // col-points dbuf (hi only, XOR-swizzled)
    int tid = threadIdx.x;
    int lane = tid & 63, w = tid >> 6;
    int l31 = lane & 31, lh = lane >> 5;
    int b = blockIdx.x & 7;
    int rt = (blockIdx.x >> 3) & 31;
    int ch = blockIdx.x >> 8;
    int r0 = rt * 128;
    int cb = ch * 1024;
    size_t bbase = (size_t)b * NPTS;

    // resident row-point fragments (second MFMA operand): lane l31 = row
    short8v Ah[4], Al[4];
    {
        const u16* pa = xth + (bbase + r0 + 32 * w + l31) * 64 + 8 * lh;
        const u16* pl = xtl + (bbase + r0 + 32 * w + l31) * 64 + 8 * lh;
#pragma unroll
        for (int s = 0; s < 4; s++) {
            Ah[s] = *(const short8v*)(pa + 16 * s);
            Al[s] = *(const short8v*)(pl + 16 * s);
        }
    }

    u32 L[16];
#pragma unroll
    for (int i = 0; i < 16; i++) L[i] = 0u;

    stage_tile(xth + (bbase + cb) * 64, pool[0], w, lane);
    __syncthreads();                    // vmcnt drained -> tile 0 ready

    for (int t = 0; t < 16; t++) {
        int n1 = cb + t * 64;
        const char* pb = pool[t & 1];
        if (t < 15)                     // issue next tile early; latency hides
            stage_tile(xth + (bbase + n1 + 64) * 64, pool[(t + 1) & 1], w, lane);

        const float* sqbp = sqb + bbase + n1 + 4 * lh;
        float16v a0, a1;                // acc init = bias row (score offset)
#pragma unroll
        for (int q = 0; q < 4; q++) {
            ((float4*)&a0)[q] = *(const float4*)(sqbp + 8 * q);
            ((float4*)&a1)[q] = *(const float4*)(sqbp + 32 + 8 * q);
        }

#pragma unroll
        for (int s = 0; s < 4; s++) {
            int gx = 2 * s + lh;
            int sw = (gx ^ (l31 & 7)) << 4;
            short8v bh0 = *(const short8v*)(pb + l31 * 128 + sw);
            a0 = MFMA32(bh0, Ah[s], a0);    // n(lane&31)=row, m(regs)=col
            a0 = MFMA32(bh0, Al[s], a0);
        }
        sel_half(a0, n1 + 4 * lh, L);

#pragma unroll
        for (int s = 0; s < 4; s++) {
            int gx = 2 * s + lh;
            int sw = (gx ^ (l31 & 7)) << 4;
            short8v bh1 = *(const short8v*)(pb + (32 + l31) * 128 + sw);
            a1 = MFMA32(bh1, Ah[s], a1);
            a1 = MFMA32(bh1, Al[s], a1);
        }
        sel_half(a1, n1 + 32 + 4 * lh, L);

        __syncthreads();                // sync + implicit vmcnt(0): next ready
    }

    // merge the row's two class-lists (partner lane = lane^32, same row l31)
    u32 M[16];
#pragma unroll
    for (int i = 0; i < 16; i++) {
        u32 pv = __shfl_xor(L[15 - i], 32);
        M[i] = umaxu(L[i], pv);
    }
#pragma unroll
    for (int j = 8; j >= 1; j >>= 1)
#pragma unroll
        for (int i = 0; i < 16; i++)
            if ((i & j) == 0) {
                int p = i | j;
                u32 a = M[i], b2 = M[p];
                M[i] = umaxu(a, b2);
                M[p] = uminu(a, b2);
            }
    if (lane < 32) {
        u32* cr = cand + (bbase + r0 + 32 * w + l31) * 64 + ch * 16;
#pragma unroll
        for (int q = 0; q < 4; q++) {
            uint4 v;
            v.x = M[4 * q]; v.y = M[4 * q + 1]; v.z = M[4 * q + 2]; v.w = M[4 * q + 3];
            *(uint4*)(cr + 4 * q) = v;
        }
    }
}

// ---------------------------------------------------------------------------
// k1: y1 only; Wt1 staged from W. (validated r10-r13)
// ---------------------------------------------------------------------------
__global__ __launch_bounds__(256) void k1_prep(const float* __restrict__ x,
                                               const float* __restrict__ W,
                                               float* __restrict__ y1) {
    __shared__ float Xt[64][128];
    __shared__ float Wt[64][64];
    int tid = threadIdx.x;
    int gr0 = blockIdx.x * 128;
    int b = gr0 >> 12;
    int n0 = gr0 & 4095;
    const float* xb = x + (size_t)b * (CDIM * NPTS) + n0;

    for (int k = 0; k < 32; k++) {
        int f = tid + 256 * k;
        int c = f >> 7, j = f & 127;
        Xt[c][j] = xb[(size_t)c * NPTS + j];
    }
    for (int k = 0; k < 16; k++) {
        int f = tid + 256 * k;
        int c = f >> 6, o = f & 63;
        Wt[c][o] = W[o * 128 + c];
    }
    __syncthreads();

    int tr = tid & 15, tc = tid >> 4;
    float acc[8][4];
#pragma unroll
    for (int i = 0; i < 8; i++)
#pragma unroll
        for (int j = 0; j < 4; j++) acc[i][j] = 0.f;

#pragma unroll 4
    for (int c = 0; c < 64; c++) {
        float a[8], bb[4];
        *(float4*)&a[0] = *(const float4*)&Xt[c][8 * tr];
        *(float4*)&a[4] = *(const float4*)&Xt[c][8 * tr + 4];
        *(float4*)&bb[0] = *(const float4*)&Wt[c][4 * tc];
#pragma unroll
        for (int i = 0; i < 8; i++)
#pragma unroll
            for (int j = 0; j < 4; j++) acc[i][j] = fmaf(a[i], bb[j], acc[i][j]);
    }

#pragma unroll
    for (int i = 0; i < 8; i++) {
        int r = gr0 + 8 * tr + i;
        float4 s0;
        s0.x = acc[i][0]; s0.y = acc[i][1]; s0.z = acc[i][2]; s0.w = acc[i][3];
        *(float4*)(y1 + (size_t)r * 64 + 4 * tc) = s0;
    }
}

// ---------------------------------------------------------------------------
// k2b3: FUSED rescore + top-20 + output. 2048 blocks x 256 thr; wave = 4 rows
// (serial). cand = 4 sorted-desc-16 runs -> 7-stage merge (reverse + 5-stage
// pairwise bitonic merge -> two sorted-32; max-half = exact top-32 SET).
// wt2 staged once per 16 rows. Coalesced 16-float output rows.
// ---------------------------------------------------------------------------
__global__ __launch_bounds__(256) void k2b3(const float* __restrict__ xtf,
                                            const float* __restrict__ sq,
                                            const u32* __restrict__ cand,
                                            const float* __restrict__ y1,
                                            const float* __restrict__ wt2g,
                                            const float* __restrict__ bias,
                                            float* __restrict__ out) {
    __shared__ float wt2[64][64];   // (W2-W1)^T : wt2[c][o]
    __shared__ float xr[4][64];
    __shared__ float dd[4][32];
    __shared__ u32 cols[4][32];
    __shared__ int ids[4][KSEL];
    __shared__ float outT[64][17];  // [o][16 n-local + pad]
    int tid = threadIdx.x;
    int lane = tid & 63, w = tid >> 6;
    int bid = blockIdx.x;
    int b = bid & 7;                       // batch == XCD slot
    int nblk = (bid >> 3) * 16;            // 16 rows per block
    size_t bbase = (size_t)b * NPTS;

    // stage wt2 coalesced (16 KB as 1024 float4s), once per 16 rows
#pragma unroll
    for (int k = 0; k < 4; k++) {
        int f = tid + 256 * k;
        ((float4*)wt2)[f] = ((const float4*)wt2g)[f];
    }
    __syncthreads();

    int s = lane & 3, g = lane >> 2;
    float bl = bias[lane];

#pragma unroll 1
    for (int i = 0; i < 4; i++) {
        int n = nblk + w * 4 + i;
        size_t row = bbase + n;

        if (lane < 16)
            *(float4*)&xr[w][lane * 4] = *(const float4*)(xtf + row * 64 + lane * 4);
        u32 key = cand[row * 64 + lane];

        // --- 7-stage exact top-32 of 4 sorted-16 runs ---
        int local = lane & 31;
        {   // reverse runs 1 and 3 (make each 32-half bitonic)
            int srcl = (local < 16) ? local : (47 - local);
            key = __shfl(key, (lane & 32) | srcl);
        }
#pragma unroll
        for (u32 j2 = 16; j2 >= 1; j2 >>= 1) {   // 5-stage merge desc per half
            u32 p = __shfl_xor(key, j2);
            key = ((local & j2) == 0) ? umaxu(key, p) : uminu(key, p);
        }
        {   // cross max-half: lanes 0-31 get top-32 SET of all 64
            u32 p = __shfl(key, 63 - lane);
            if (lane < 32) cols[w][lane] = umaxu(key, p) & 0xFFFu;
        }

        // cooperative exact rescore: 2 passes x 16 candidates, 4 lanes each
        float4 xq[4];
#pragma unroll
        for (int q = 0; q < 4; q++) xq[q] = *(const float4*)&xr[w][16 * q + 4 * s];

#pragma unroll
        for (int p = 0; p < 2; p++) {
            int m = cols[w][p * 16 + g];
            const float* pm = xtf + (bbase + m) * 64;
            float d = 0.f;
#pragma unroll
            for (int q = 0; q < 4; q++) {
                float4 v = *(const float4*)(pm + 16 * q + 4 * s);
                d = fmaf(v.x, xq[q].x, d); d = fmaf(v.y, xq[q].y, d);
                d = fmaf(v.z, xq[q].z, d); d = fmaf(v.w, xq[q].w, d);
            }
            d += __shfl_xor(d, 1);
            d += __shfl_xor(d, 2);
            if (s == 0) dd[w][p * 16 + g] = d;
        }

        // exact u64 keys + top-20: 32-wide bitonic (lanes >=32 sentinels)
        u64 kE = 0;
        if (lane < 32) {
            int m = (int)cols[w][lane];
            float sE = fmaf(2.f, dd[w][lane], -sq[bbase + m]);
            kE = ((u64)ordf(sE) << 32) | (u32)(~(u32)m);
        }
#pragma unroll
        for (u32 k = 2; k <= 32; k <<= 1) {
#pragma unroll
            for (u32 j2 = k >> 1; j2 >= 1; j2 >>= 1) {
                bool up = ((lane & k) == 0);
                bool lower = ((lane & j2) == 0);
                u64 p = __shfl_xor(kE, j2);
                u64 mx = (kE > p) ? kE : p, mn = (kE > p) ? p : kE;
                kE = (lower == up) ? mx : mn;
            }
        }
        if (lane < KSEL) ids[w][lane] = (int)(~(u32)kE);

        // output row: max_k y1[m_k][o] + xr.wt2[:,o] + bias[o]
        const float* y1b = y1 + bbase * 64;
        float acc = -FLT_MAX;
#pragma unroll
        for (int k = 0; k < KSEL; k++) {
            int m = ids[w][k];
            acc = fmaxf(acc, y1b[(size_t)m * 64 + lane]);
        }
        float acc2 = 0.f;
#pragma unroll 8
        for (int c = 0; c < 64; c++)
            acc2 = fmaf(xr[w][c], wt2[c][lane], acc2);
        outT[lane][w * 4 + i] = acc + acc2 + bl;
    }
    __syncthreads();

    {   // coalesced store: thread (o = tid&63, q = tid>>6) writes 4 floats
        int o = tid & 63, q = tid >> 6;
        float4 v;
        v.x = outT[o][q * 4 + 0]; v.y = outT[o][q * 4 + 1];
        v.z = outT[o][q * 4 + 2]; v.w = outT[o][q * 4 + 3];
        *(float4*)(out + ((size_t)(b * 64 + o)) * NPTS + nblk + q * 4) = v;
    }
}

// ---------------------------------------------------------------------------
extern "C" void kernel_launch(void* const* d_in, const int* in_sizes, int n_in,
                              void* d_out, int out_size, void* d_ws, size_t ws_size,
                              hipStream_t stream) {
    const float* x    = (const float*)d_in[0];   // (8, 64, 4096)
    const float* W    = (const float*)d_in[1];   // (64, 128)
    const float* bias = (const float*)d_in[2];   // (64,)
    float* out = (float*)d_out;                  // (8, 64, 4096)
    float* ws = (float*)d_ws;

    u16* xth    = (u16*)ws;                 // [0,4MB)   dies after k2
    u16* xtl    = (u16*)(ws + F_XTL);       // [4,8MB)   dies after k2
    u32* candb  = (u32*)(ws + F_CAND);      // [8,16MB)
    float* xtf  = ws + F_XTF;               // [16,24MB)
    float* sq   = ws + F_SQ;                // 128 KB
    float* wt2g = ws + F_WT2;               // 16 KB
    float* sqb  = ws + F_SQB;               // 128 KB
    float* y1   = ws;                       // overlays xth/xtl after k2

    hipLaunchKernelGGL(p1_prep, dim3(528),  dim3(256), 0, stream,
                       x, W, xtf, xth, xtl, sq, sqb, wt2g);
    hipLaunchKernelGGL(k2_gram, dim3(1024), dim3(256), 0, stream, xth, xtl, sqb, candb);
    hipLaunchKernelGGL(k1_prep, dim3(256),  dim3(256), 0, stream, x, W, y1);
    hipLaunchKernelGGL(k2b3,    dim3(2048), dim3(256), 0, stream,
                       xtf, sq, candb, y1, wt2g, bias, out);
}

// Round 16
// 133.457 us; speedup vs baseline: 1.8593x; 1.0617x over previous
//
#include <hip/hip_runtime.h>
#include <float.h>

typedef unsigned long long u64;
typedef unsigned int u32;
typedef unsigned short u16;

#define NPTS 4096
#define CDIM 64
#define BATCH 8
#define KSEL 20

// ws layout in float-slots (total ~25.4 MB; r9 proved ws >= 26.6 MB):
#define F_XTL (BATCH * NPTS * 32)               // 1M floats
#define F_CAND (2 * BATCH * NPTS * 32)          // 2M
#define F_XTF (4 * BATCH * NPTS * 32)          // 4M
#define F_SQ (6 * BATCH * NPTS * 32)            // 6M
#define F_WT2 (F_SQ + BATCH * NPTS)             // +32K
#define F_SQB (F_WT2 + 64 * 64)                 // +4K

typedef __attribute__((ext_vector_type(8))) short short8v;   // 8 bf16 (4 VGPR)
typedef __attribute__((ext_vector_type(16))) float float16v; // MFMA 32x32 acc

#define MFMA32(a, b, c) __builtin_amdgcn_mfma_f32_32x32x16_bf16(a, b, c, 0, 0, 0)

__device__ __forceinline__ u32 ordf(float f) {
    u32 u = __float_as_uint(f);
    return (u >> 31) ? ~u : (u | 0x80000000u);
}
__device__ __forceinline__ u32 umaxu(u32 a, u32 b) { return a > b ? a : b; }
__device__ __forceinline__ u32 uminu(u32 a, u32 b) { return a < b ? a : b; }

__device__ __forceinline__ void load_lds_16(const void* g, void* l) {
    __builtin_amdgcn_global_load_lds(
        (const __attribute__((address_space(1))) unsigned int*)g,
        (__attribute__((address_space(3))) unsigned int*)l, 16, 0, 0);
}

#define CE(i, j) { u32 a_ = c[i], b_ = c[j]; c[i] = umaxu(a_, b_); c[j] = uminu(a_, b_); }

// Batcher odd-even merge sort, 16 u32 keys, descending. 63 CEs. (validated r7-r14)
__device__ __forceinline__ void sort16_desc(u32 (&c)[16]) {
    CE(0,1) CE(2,3) CE(4,5) CE(6,7) CE(8,9) CE(10,11) CE(12,13) CE(14,15)
    CE(0,2) CE(1,3) CE(4,6) CE(5,7) CE(8,10) CE(9,11) CE(12,14) CE(13,15)
    CE(1,2) CE(5,6) CE(9,10) CE(13,14)
    CE(0,4) CE(1,5) CE(2,6) CE(3,7) CE(8,12) CE(9,13) CE(10,14) CE(11,15)
    CE(2,4) CE(3,5) CE(10,12) CE(11,13)
    CE(1,2) CE(3,4) CE(5,6) CE(9,10) CE(11,12) CE(13,14)
    CE(0,8) CE(1,9) CE(2,10) CE(3,11) CE(4,12) CE(5,13) CE(6,14) CE(7,15)
    CE(4,8) CE(5,9) CE(6,10) CE(7,11)
    CE(2,4) CE(3,5) CE(6,8) CE(7,9) CE(10,12) CE(11,13)
    CE(1,2) CE(3,4) CE(5,6) CE(7,8) CE(9,10) CE(11,12) CE(13,14)
}
#undef CE

// L (desc,16) <- top-16 of L ∪ c (desc,16): max-half + bitonic merge
__device__ __forceinline__ void merge_into16(u32 (&L)[16], const u32 (&c)[16]) {
#pragma unroll
    for (int i = 0; i < 16; i++) L[i] = umaxu(L[i], c[15 - i]);
#pragma unroll
    for (int j = 8; j >= 1; j >>= 1)
#pragma unroll
        for (int i = 0; i < 16; i++)
            if ((i & j) == 0) {
                int p = i | j;
                u32 a = L[i], b = L[p];
                L[i] = umaxu(a, b);
                L[p] = uminu(a, b);
            }
}

// ---------------------------------------------------------------------------
// p1 (+k0 folded): blocks <512: transpose x -> xtf, xth/xtl (bf16 split of
// sqrt(2)x), sq, sqb=1024-sq. blocks >=512: wt2g. (validated r13-r14)
// ---------------------------------------------------------------------------
__global__ __launch_bounds__(256) void p1_prep(const float* __restrict__ x,
                                               const float* __restrict__ W,
                                               float* __restrict__ xtf,
                                               u16* __restrict__ xth,
                                               u16* __restrict__ xtl,
                                               float* __restrict__ sq,
                                               float* __restrict__ sqb,
                                               float* __restrict__ wt2g) {
    __shared__ float Xp[64][65];
    int tid = threadIdx.x;
    if (blockIdx.x >= 512) {                    // k0 branch (16 blocks)
        int f = (blockIdx.x - 512) * 256 + tid;
        if (f < 64 * 64) {
            int c = f >> 6, o = f & 63;
            wt2g[f] = W[o * 128 + 64 + c] - W[o * 128 + c];
        }
        return;
    }
    int b = blockIdx.x >> 6;
    int n0 = (blockIdx.x & 63) * 64;
    const float* xb = x + (size_t)b * (CDIM * NPTS);
    int j = tid & 63, cq = tid >> 6;
#pragma unroll
    for (int i = 0; i < 16; i++) {
        int c = cq * 16 + i;
        Xp[c][j] = xb[(size_t)c * NPTS + n0 + j];
    }
    __syncthreads();
    if (tid < 64) {
        float s = 0.f;
        for (int c = 0; c < 64; c++) { float v = Xp[c][tid]; s = fmaf(v, v, s); }
        sq[(size_t)b * NPTS + n0 + tid] = s;
        sqb[(size_t)b * NPTS + n0 + tid] = 1024.f - s;
    }
    int n = tid >> 2, c0 = (tid & 3) * 16;
    float vv[16];
#pragma unroll
    for (int i = 0; i < 16; i++) vv[i] = Xp[c0 + i][n];
    size_t rowb = ((size_t)b * NPTS + n0 + n) * 64 + c0;
#pragma unroll
    for (int q = 0; q < 4; q++) {
        float4 f;
        f.x = vv[4 * q]; f.y = vv[4 * q + 1]; f.z = vv[4 * q + 2]; f.w = vv[4 * q + 3];
        *(float4*)(xtf + rowb + 4 * q) = f;
    }
    u16 hb[16], lb[16];
#pragma unroll
    for (int i = 0; i < 16; i++) {
        float v = vv[i] * 1.41421356237f;       // sqrt(2) pre-scale: MFMA = 2*dot
        u32 bv = __float_as_uint(v);
        u32 h = (bv + 0x7FFFu + ((bv >> 16) & 1u)) >> 16;    // RNE bf16
        float hf = __uint_as_float(h << 16);
        float lf = v - hf;
        u32 bl = __float_as_uint(lf);
        u32 lo = (bl + 0x7FFFu + ((bl >> 16) & 1u)) >> 16;
        hb[i] = (u16)h; lb[i] = (u16)lo;
    }
    uint4 H0, H1, L0, L1;
    H0.x = hb[0] | ((u32)hb[1] << 16);  H0.y = hb[2] | ((u32)hb[3] << 16);
    H0.z = hb[4] | ((u32)hb[5] << 16);  H0.w = hb[6] | ((u32)hb[7] << 16);
    H1.x = hb[8] | ((u32)hb[9] << 16);  H1.y = hb[10] | ((u32)hb[11] << 16);
    H1.z = hb[12] | ((u32)hb[13] << 16); H1.w = hb[14] | ((u32)hb[15] << 16);
    L0.x = lb[0] | ((u32)lb[1] << 16);  L0.y = lb[2] | ((u32)lb[3] << 16);
    L0.z = lb[4] | ((u32)lb[5] << 16);  L0.w = lb[6] | ((u32)lb[7] << 16);
    L1.x = lb[8] | ((u32)lb[9] << 16);  L1.y = lb[10] | ((u32)lb[11] << 16);
    L1.z = lb[12] | ((u32)lb[13] << 16); L1.w = lb[14] | ((u32)lb[15] << 16);
    *(uint4*)(xth + rowb) = H0;
    *(uint4*)(xth + rowb + 8) = H1;
    *(uint4*)(xtl + rowb) = L0;
    *(uint4*)(xtl + rowb + 8) = L1;
}

// ---------------------------------------------------------------------------
// k2: swapped-operand MFMA Gram, bias-in-accumulator, 1-PRODUCT screening
// (Ah*Bh only; dropped-term rms ~0.045 << 0.25 quant bin + 12-slot rescore
// margin — call-1 of r15 validated absmax 0.015625). Staging reverted to the
// r13-proven SINGLE-buffer two-barrier pattern (r14/r15's one-barrier dbuf is
// the prime race suspect for r15's replay divergence).
// ---------------------------------------------------------------------------
__device__ __forceinline__ void stage_tile(const u16* __restrict__ srcb,
                                           char* lds, int w, int lane) {
#pragma unroll
    for (int i = 0; i < 2; i++) {
        int G = w * 128 + i * 64 + lane;
        int rr = G >> 3, gp = G & 7;
        const u16* src = srcb + rr * 64 + ((gp ^ (rr & 7)) << 3);
        char* dst = lds + (w * 128 + i * 64) * 16;
        load_lds_16(src, dst);
    }
}

// keys straight from biased acc regs: col(r) = colbase2 + 8*(r>>2) + (r&3)
__device__ __forceinline__ void sel_half(const float16v& A, int colbase2,
                                         u32 (&L)[16]) {
    u32 c[16];
#pragma unroll
    for (int q = 0; q < 4; q++) {
        u32 cg = (u32)(colbase2 + 8 * q);
        c[4 * q + 0] = (__float_as_uint(A[4 * q + 0]) & 0xFFFFF000u) | (cg + 0);
        c[4 * q + 1] = (__float_as_uint(A[4 * q + 1]) & 0xFFFFF000u) | (cg + 1);
        c[4 * q + 2] = (__float_as_uint(A[4 * q + 2]) & 0xFFFFF000u) | (cg + 2);
        c[4 * q + 3] = (__float_as_uint(A[4 * q + 3]) & 0xFFFFF000u) | (cg + 3);
    }
    sort16_desc(c);
    merge_into16(L, c);
}

__global__ __launch_bounds__(256, 4) void k2_gram(const u16* __restrict__ xth,
                                                  const float* __restrict__ sqb,
                                                  u32* __restrict__ cand) {
    __shared__ char pool[8192];        // col-points tile (hi only, XOR-swizzled)
    int tid = threadIdx.x;
    int lane = tid & 63, w = tid >> 6;
    int l31 = lane & 31, lh = lane >> 5;
    int b = blockIdx.x & 7;
    int rt = (blockIdx.x >> 3) & 31;
    int ch = blockIdx.x >> 8;
    int r0 = rt * 128;
    int cb = ch * 1024;
    size_t bbase = (size_t)b * NPTS;

    // resident row-point fragments (hi only): lane l31 = row
    short8v Ah[4];
    {
        const u16* pa = xth + (bbase + r0 + 32 * w + l31) * 64 + 8 * lh;
#pragma unroll
        for (int s = 0; s < 4; s++) Ah[s] = *(const short8v*)(pa + 16 * s);
    }

    u32 L[16];
#pragma unroll
    for (int i = 0; i < 16; i++) L[i] = 0u;

    // sqb prefetch regs for current tile (deterministic; r15 call-1-validated)
    float4 sqn[8];
    {
        const float* p0 = sqb + bbase + cb + 4 * lh;
#pragma unroll
        for (int q = 0; q < 4; q++) {
            sqn[q] = *(const float4*)(p0 + 8 * q);
            sqn[4 + q] = *(const float4*)(p0 + 32 + 8 * q);
        }
    }

    stage_tile(xth + (bbase + cb) * 64, pool, w, lane);
    __syncthreads();                    // vmcnt drained -> tile 0 ready

    for (int t = 0; t < 16; t++) {
        int n1 = cb + t * 64;

        float16v a0, a1;                // acc init = biased row from prefetch
#pragma unroll
        for (int q = 0; q < 4; q++) {
            ((float4*)&a0)[q] = sqn[q];
            ((float4*)&a1)[q] = sqn[4 + q];
        }
        if (t < 15) {                   // prefetch next tile's sqb into regs
            const float* np = sqb + bbase + n1 + 64 + 4 * lh;
#pragma unroll
            for (int q = 0; q < 4; q++) {
                sqn[q] = *(const float4*)(np + 8 * q);
                sqn[4 + q] = *(const float4*)(np + 32 + 8 * q);
            }
        }

#pragma unroll
        for (int s = 0; s < 4; s++) {
            int gx = 2 * s + lh;
            int sw = (gx ^ (l31 & 7)) << 4;
            short8v bh0 = *(const short8v*)(pool + l31 * 128 + sw);
            a0 = MFMA32(bh0, Ah[s], a0);    // n(lane&31)=row, m(regs)=col
        }
        sel_half(a0, n1 + 4 * lh, L);

#pragma unroll
        for (int s = 0; s < 4; s++) {
            int gx = 2 * s + lh;
            int sw = (gx ^ (l31 & 7)) << 4;
            short8v bh1 = *(const short8v*)(pool + (32 + l31) * 128 + sw);
            a1 = MFMA32(bh1, Ah[s], a1);
        }
        __syncthreads();                // all waves done reading pool
        if (t < 15)
            stage_tile(xth + (bbase + n1 + 64) * 64, pool, w, lane);
        sel_half(a1, n1 + 32 + 4 * lh, L);   // hides staging latency
        __syncthreads();                // drains vmcnt -> next tile ready
    }

    // merge the row's two class-lists (partner lane = lane^32, same row l31)
    u32 M[16];
#pragma unroll
    for (int i = 0; i < 16; i++) {
        u32 pv = __shfl_xor(L[15 - i], 32);
        M[i] = umaxu(L[i], pv);
    }
#pragma unroll
    for (int j = 8; j >= 1; j >>= 1)
#pragma unroll
        for (int i = 0; i < 16; i++)
            if ((i & j) == 0) {
                int p = i | j;
                u32 a = M[i], b2 = M[p];
                M[i] = umaxu(a, b2);
                M[p] = uminu(a, b2);
            }
    if (lane < 32) {
        u32* cr = cand + (bbase + r0 + 32 * w + l31) * 64 + ch * 16;
#pragma unroll
        for (int q = 0; q < 4; q++) {
            uint4 v;
            v.x = M[4 * q]; v.y = M[4 * q + 1]; v.z = M[4 * q + 2]; v.w = M[4 * q + 3];
            *(uint4*)(cr + 4 * q) = v;
        }
    }
}

// ---------------------------------------------------------------------------
// k1: y1 only; Wt1 staged from W. Separate launch (r10-r14 validated; the
// r15 p1-fusion is a race suspect and is reverted).
// ---------------------------------------------------------------------------
__global__ __launch_bounds__(256) void k1_prep(const float* __restrict__ x,
                                               const float* __restrict__ W,
                                               float* __restrict__ y1) {
    __shared__ float Xt[64][128];
    __shared__ float Wt[64][64];
    int tid = threadIdx.x;
    int gr0 = blockIdx.x * 128;
    int b = gr0 >> 12;
    int n0 = gr0 & 4095;
    const float* xb = x + (size_t)b * (CDIM * NPTS) + n0;

    for (int k = 0; k < 32; k++) {
        int f = tid + 256 * k;
        int c = f >> 7, j = f & 127;
        Xt[c][j] = xb[(size_t)c * NPTS + j];
    }
    for (int k = 0; k < 16; k++) {
        int f = tid + 256 * k;
        int c = f >> 6, o = f & 63;
        Wt[c][o] = W[o * 128 + c];
    }
    __syncthreads();

    int tr = tid & 15, tc = tid >> 4;
    float acc[8][4];
#pragma unroll
    for (int i = 0; i < 8; i++)
#pragma unroll
        for (int j = 0; j < 4; j++) acc[i][j] = 0.f;

#pragma unroll 4
    for (int c = 0; c < 64; c++) {
        float a[8], bb[4];
        *(float4*)&a[0] = *(const float4*)&Xt[c][8 * tr];
        *(float4*)&a[4] = *(const float4*)&Xt[c][8 * tr + 4];
        *(float4*)&bb[0] = *(const float4*)&Wt[c][4 * tc];
#pragma unroll
        for (int i = 0; i < 8; i++)
#pragma unroll
            for (int j = 0; j < 4; j++) acc[i][j] = fmaf(a[i], bb[j], acc[i][j]);
    }

#pragma unroll
    for (int i = 0; i < 8; i++) {
        int r = gr0 + 8 * tr + i;
        float4 s0;
        s0.x = acc[i][0]; s0.y = acc[i][1]; s0.z = acc[i][2]; s0.w = acc[i][3];
        *(float4*)(y1 + (size_t)r * 64 + 4 * tc) = s0;
    }
}

// ---------------------------------------------------------------------------
// k2b3: FUSED rescore + top-20 + output. (byte-identical to r14-validated)
// ---------------------------------------------------------------------------
__global__ __launch_bounds__(256) void k2b3(const float* __restrict__ xtf,
                                            const float* __restrict__ sq,
                                            const u32* __restrict__ cand,
                                            const float* __restrict__ y1,
                                            const float* __restrict__ wt2g,
                                            const float* __restrict__ bias,
                                            float* __restrict__ out) {
    __shared__ float wt2[64][64];   // (W2-W1)^T : wt2[c][o]
    __shared__ float xr[4][64];
    __shared__ float dd[4][32];
    __shared__ u32 cols[4][32];
    __shared__ int ids[4][KSEL];
    __shared__ float outT[64][17];  // [o][16 n-local + pad]
    int tid = threadIdx.x;
    int lane = tid & 63, w = tid >> 6;
    int bid = blockIdx.x;
    int b = bid & 7;                       // batch == XCD slot
    int nblk = (bid >> 3) * 16;            // 16 rows per block
    size_t bbase = (size_t)b * NPTS;

#pragma unroll
    for (int k = 0; k < 4; k++) {
        int f = tid + 256 * k;
        ((float4*)wt2)[f] = ((const float4*)wt2g)[f];
    }
    __syncthreads();

    int s = lane & 3, g = lane >> 2;
    float bl = bias[lane];

#pragma unroll 1
    for (int i = 0; i < 4; i++) {
        int n = nblk + w * 4 + i;
        size_t row = bbase + n;

        if (lane < 16)
            *(float4*)&xr[w][lane * 4] = *(const float4*)(xtf + row * 64 + lane * 4);
        u32 key = cand[row * 64 + lane];

        // --- 7-stage exact top-32 of 4 sorted-16 runs ---
        int local = lane & 31;
        {   // reverse runs 1 and 3 (make each 32-half bitonic)
            int srcl = (local < 16) ? local : (47 - local);
            key = __shfl(key, (lane & 32) | srcl);
        }
#pragma unroll
        for (u32 j2 = 16; j2 >= 1; j2 >>= 1) {   // 5-stage merge desc per half
            u32 p = __shfl_xor(key, j2);
            key = ((local & j2) == 0) ? umaxu(key, p) : uminu(key, p);
        }
        {   // cross max-half: lanes 0-31 get top-32 SET of all 64
            u32 p = __shfl(key, 63 - lane);
            if (lane < 32) cols[w][lane] = umaxu(key, p) & 0xFFFu;
        }

        // cooperative exact rescore: 2 passes x 16 candidates, 4 lanes each
        float4 xq[4];
#pragma unroll
        for (int q = 0; q < 4; q++) xq[q] = *(const float4*)&xr[w][16 * q + 4 * s];

#pragma unroll
        for (int p = 0; p < 2; p++) {
            int m = cols[w][p * 16 + g];
            const float* pm = xtf + (bbase + m) * 64;
            float d = 0.f;
#pragma unroll
            for (int q = 0; q < 4; q++) {
                float4 v = *(const float4*)(pm + 16 * q + 4 * s);
                d = fmaf(v.x, xq[q].x, d); d = fmaf(v.y, xq[q].y, d);
                d = fmaf(v.z, xq[q].z, d); d = fmaf(v.w, xq[q].w, d);
            }
            d += __shfl_xor(d, 1);
            d += __shfl_xor(d, 2);
            if (s == 0) dd[w][p * 16 + g] = d;
        }

        // exact u64 keys + top-20: 32-wide bitonic (lanes >=32 sentinels)
        u64 kE = 0;
        if (lane < 32) {
            int m = (int)cols[w][lane];
            float sE = fmaf(2.f, dd[w][lane], -sq[bbase + m]);
            kE = ((u64)ordf(sE) << 32) | (u32)(~(u32)m);
        }
#pragma unroll
        for (u32 k = 2; k <= 32; k <<= 1) {
#pragma unroll
            for (u32 j2 = k >> 1; j2 >= 1; j2 >>= 1) {
                bool up = ((lane & k) == 0);
                bool lower = ((lane & j2) == 0);
                u64 p = __shfl_xor(kE, j2);
                u64 mx = (kE > p) ? kE : p, mn = (kE > p) ? p : kE;
                kE = (lower == up) ? mx : mn;
            }
        }
        if (lane < KSEL) ids[w][lane] = (int)(~(u32)kE);

        // output row: max_k y1[m_k][o] + xr.wt2[:,o] + bias[o]
        const float* y1b = y1 + bbase * 64;
        float acc = -FLT_MAX;
#pragma unroll
        for (int k = 0; k < KSEL; k++) {
            int m = ids[w][k];
            acc = fmaxf(acc, y1b[(size_t)m * 64 + lane]);
        }
        float acc2 = 0.f;
#pragma unroll 8
        for (int c = 0; c < 64; c++)
            acc2 = fmaf(xr[w][c], wt2[c][lane], acc2);
        outT[lane][w * 4 + i] = acc + acc2 + bl;
    }
    __syncthreads();

    {   // coalesced store: thread (o = tid&63, q = tid>>6) writes 4 floats
        int o = tid & 63, q = tid >> 6;
        float4 v;
        v.x = outT[o][q * 4 + 0]; v.y = outT[o][q * 4 + 1];
        v.z = outT[o][q * 4 + 2]; v.w = outT[o][q * 4 + 3];
        *(float4*)(out + ((size_t)(b * 64 + o)) * NPTS + nblk + q * 4) = v;
    }
}

// ---------------------------------------------------------------------------
extern "C" void kernel_launch(void* const* d_in, const int* in_sizes, int n_in,
                              void* d_out, int out_size, void* d_ws, size_t ws_size,
                              hipStream_t stream) {
    const float* x    = (const float*)d_in[0];   // (8, 64, 4096)
    const float* W    = (const float*)d_in[1];   // (64, 128)
    const float* bias = (const float*)d_in[2];   // (64,)
    float* out = (float*)d_out;                  // (8, 64, 4096)
    float* ws = (float*)d_ws;

    u16* xth    = (u16*)ws;                 // [0,4MB)   dies after k2
    u16* xtl    = (u16*)(ws + F_XTL);       // [4,8MB)   dies after k2
    u32* candb  = (u32*)(ws + F_CAND);      // [8,16MB)
    float* xtf  = ws + F_XTF;               // [16,24MB)
    float* sq   = ws + F_SQ;                // 128 KB
    float* wt2g = ws + F_WT2;               // 16 KB
    float* sqb  = ws + F_SQB;               // 128 KB
    float* y1   = ws;                       // overlays xth/xtl after k2

    hipLaunchKernelGGL(p1_prep, dim3(528),  dim3(256), 0, stream,
                       x, W, xtf, xth, xtl, sq, sqb, wt2g);
    hipLaunchKernelGGL(k2_gram, dim3(1024), dim3(256), 0, stream, xth, sqb, candb);
    hipLaunchKernelGGL(k1_prep, dim3(256),  dim3(256), 0, stream, x, W, y1);
    hipLaunchKernelGGL(k2b3,    dim3(2048), dim3(256), 0, stream,
                       xtf, sq, candb, y1, wt2g, bias, out);
}